// Round 4
// baseline (291.923 us; speedup 1.0000x reference)
//
#include <hip/hip_runtime.h>
#include <hip/hip_bf16.h>

// ---------------------------------------------------------------------------
// RnnGruModel: MLP (1600->60->15->10) fused with GRU-layer0 input-gate
// precompute, then 3 stacked GRU layers (H=5) + output projection.
// X@W1^T done in bf16 MFMA with hi/lo split (3 products) -> ~fp32 accuracy.
// GRU: 3 layers fused into ONE 256-step scan; 8 lanes per batch element,
// lane j owns h_j; h broadcast via 5 independent ds_bpermute.
// Layouts: X (T,B,F) row-major, row r = t*128 + b.  Output (T,1,B): t*128+b.
// ---------------------------------------------------------------------------

#define T_DIM 256
#define B_DIM 128
#define F_DIM 1600
#define H1_DIM 60
#define H2_DIM 15
#define H3_DIM 10
#define GH 5
#define NSTEP 50          // K-steps of 32 (1600/32)

typedef __attribute__((ext_vector_type(8))) short bf16x8;   // MFMA A/B frag (4 VGPRs)
typedef __attribute__((ext_vector_type(4))) float f32x4;    // MFMA C/D frag

__device__ __forceinline__ float fast_tanh(float x) {
    float e = __expf(2.0f * x);
    return 1.0f - __fdividef(2.0f, e + 1.0f);   // safe at +-inf
}
__device__ __forceinline__ float fast_sigmoid(float x) {
    return __fdividef(1.0f, 1.0f + __expf(-x)); // safe at +-inf
}
__device__ __forceinline__ ushort f2bf_rn(float x) {        // round-to-nearest bf16
    uint u = __float_as_uint(x);
    u += 0x7fffu + ((u >> 16) & 1u);
    return (ushort)(u >> 16);
}

// ---------------------------------------------------------------------------
// Kernel 0: pack W1 (60x1600 fp32, zero-padded to 64 rows) into frag-ordered
// bf16 hi/lo pairs. Frag f = s*8 + nf*2 + h (s=K-step, nf=N-frag, h=hi/lo);
// within a frag, lane l holds 8 bf16 of B[k = s*32 + (l>>4)*8 + j][n = nf*16
// + (l&15)] = W1[n][k]. A-frags use the SAME (lane-group, slot)->k map, so
// the product is correct regardless of the HW's internal k permutation.
// ---------------------------------------------------------------------------
__global__ __launch_bounds__(256) void pack_w1_kernel(
    const float* __restrict__ W1, ushort* __restrict__ Wp)
{
    const int s  = blockIdx.x;       // 0..49
    const int t  = threadIdx.x;
    const int nf = t >> 6;
    const int l  = t & 63;
    const int n  = nf * 16 + (l & 15);
    const int g  = l >> 4;

    ushort hi[8], lo[8];
#pragma unroll
    for (int j = 0; j < 8; ++j) {
        const int k = s * 32 + g * 8 + j;
        const float v = (n < H1_DIM) ? W1[n * F_DIM + k] : 0.0f;
        const ushort h = f2bf_rn(v);
        const float hf = __uint_as_float(((uint)h) << 16);
        const float r  = v - hf;                       // exact
        hi[j] = h;
        lo[j] = (ushort)(__float_as_uint(r) >> 16);    // truncate: |err| ~ 2^-17 |v|
    }
    ushort* dst = Wp + ((size_t)(s * 8 + nf * 2)) * 512 + l * 8;
#pragma unroll
    for (int j = 0; j < 8; ++j) dst[j] = hi[j];
#pragma unroll
    for (int j = 0; j < 8; ++j) dst[512 + j] = lo[j];
}

// ---------------------------------------------------------------------------
// Kernel 1: per-row MLP + gi0 precompute, MFMA edition.
// Grid: 512 blocks x 256 threads. Block owns 64 rows (4 M-frags of 16);
// the 4 waves split the 50 K-steps (12/13/12/13) and all compute the same
// 64x64 C-tile; partial C reduced through LDS. fp32 tail on wave 0.
// ---------------------------------------------------------------------------
__global__ __launch_bounds__(256) void mlp_kernel(
    const float* __restrict__ X,
    const ushort* __restrict__ Wp,
    const float* __restrict__ b1,
    const float* __restrict__ W2, const float* __restrict__ b2,
    const float* __restrict__ W3, const float* __restrict__ b3,
    const float* __restrict__ wih0, const float* __restrict__ bih0,
    float* __restrict__ gi0)
{
    __shared__ float red[4 * 4096];   // 64 KB: per-wave 64x64 C partials

    const int tid  = threadIdx.x;
    const int l    = tid & 63;
    const int w    = __builtin_amdgcn_readfirstlane(tid >> 6);
    const int lm   = l & 15;          // A-row / B-col lane index
    const int g    = l >> 4;          // k-slot group
    const int row0 = blockIdx.x * 64;

    f32x4 acc[4][4];
#pragma unroll
    for (int mf = 0; mf < 4; ++mf)
#pragma unroll
        for (int nf = 0; nf < 4; ++nf)
            acc[mf][nf] = (f32x4){0.f, 0.f, 0.f, 0.f};

    const int s0 = (w * NSTEP) >> 2;        // 0,12,25,37
    const int s1 = ((w + 1) * NSTEP) >> 2;  // 12,25,37,50

    for (int s = s0; s < s1; ++s) {
        // B frags: per-lane 16B loads, coalesced, L2-resident (400 KB total)
        bf16x8 bh[4], bl[4];
        const ushort* wp_s = Wp + (size_t)s * 4096 + l * 8;
#pragma unroll
        for (int nf = 0; nf < 4; ++nf) {
            bh[nf] = *(const bf16x8*)(wp_s + (nf * 2 + 0) * 512);
            bl[nf] = *(const bf16x8*)(wp_s + (nf * 2 + 1) * 512);
        }
        // A frags: 8 consecutive fp32 per lane per M-frag, convert to hi/lo
        bf16x8 a_hi[4], a_lo[4];
#pragma unroll
        for (int mf = 0; mf < 4; ++mf) {
            const float* ap = X + (size_t)(row0 + mf * 16 + lm) * F_DIM + s * 32 + g * 8;
            const float4 x0 = *(const float4*)ap;
            const float4 x1 = *(const float4*)(ap + 4);
            const float xs8[8] = {x0.x, x0.y, x0.z, x0.w, x1.x, x1.y, x1.z, x1.w};
            bf16x8 ah, al;
#pragma unroll
            for (int j = 0; j < 8; ++j) {
                const float v = xs8[j];
                const uint  u = __float_as_uint(v);
                const uint uh = (u + 0x7fffu + ((u >> 16) & 1u)) & 0xffff0000u;
                const float hf = __uint_as_float(uh);
                const float r  = v - hf;               // exact
                ah[j] = (short)(uh >> 16);
                al[j] = (short)(__float_as_uint(r) >> 16);
            }
            a_hi[mf] = ah; a_lo[mf] = al;
        }
        // 3-product bf16 emulation of fp32 GEMM
#pragma unroll
        for (int mf = 0; mf < 4; ++mf)
#pragma unroll
            for (int nf = 0; nf < 4; ++nf) {
                f32x4 c = acc[mf][nf];
                c = __builtin_amdgcn_mfma_f32_16x16x32_bf16(a_lo[mf], bh[nf], c, 0, 0, 0);
                c = __builtin_amdgcn_mfma_f32_16x16x32_bf16(a_hi[mf], bl[nf], c, 0, 0, 0);
                c = __builtin_amdgcn_mfma_f32_16x16x32_bf16(a_hi[mf], bh[nf], c, 0, 0, 0);
                acc[mf][nf] = c;
            }
    }

    // -------- per-wave C partials -> LDS (C/D map: col=lane&15, row=(l>>4)*4+q)
    float* myred = red + w * 4096;
#pragma unroll
    for (int mf = 0; mf < 4; ++mf)
#pragma unroll
        for (int nf = 0; nf < 4; ++nf)
#pragma unroll
            for (int q = 0; q < 4; ++q)
                myred[(mf * 16 + g * 4 + q) * 64 + nf * 16 + lm] = acc[mf][nf][q];
    __syncthreads();

    // -------- cross-wave reduce (coalesced, conflict-free), write padded ----
    float rsum[16];
#pragma unroll
    for (int i = 0; i < 16; ++i) {
        const int p = tid + 256 * i;
        rsum[i] = red[p] + red[4096 + p] + red[8192 + p] + red[12288 + p];
    }
    __syncthreads();
    float* redp = red + 8192;              // 64 x 65 padded, fits in regions 2-3
#pragma unroll
    for (int i = 0; i < 16; ++i) {
        const int p = tid + 256 * i;
        redp[(p >> 6) * 65 + (p & 63)] = rsum[i];
    }
    __syncthreads();
    if (w != 0) return;

    // ---------------- MLP tail + gi0 (wave 0, lane = row) ------------------
    float h1v[H1_DIM];
#pragma unroll
    for (int o = 0; o < H1_DIM; ++o)
        h1v[o] = fast_tanh(redp[l * 65 + o] + b1[o]);

    float h2v[H2_DIM];
#pragma unroll
    for (int j = 0; j < H2_DIM; ++j) {
        float sacc = b2[j];
#pragma unroll
        for (int o = 0; o < H1_DIM; ++o) sacc += W2[j * H1_DIM + o] * h1v[o];
        h2v[j] = fast_tanh(sacc);
    }

    float h3v[H3_DIM];
#pragma unroll
    for (int m = 0; m < H3_DIM; ++m) {
        float sacc = b3[m];
#pragma unroll
        for (int j = 0; j < H2_DIM; ++j) sacc += W3[m * H2_DIM + j] * h2v[j];
        h3v[m] = sacc;
    }

    float gv[15];
#pragma unroll
    for (int q = 0; q < 15; ++q) {
        float sacc = bih0[q];
#pragma unroll
        for (int m = 0; m < H3_DIM; ++m) sacc += wih0[q * H3_DIM + m] * h3v[m];
        gv[q] = sacc;
    }

    const int row = row0 + l;
    float4* dst = (float4*)(gi0 + (size_t)row * 16);
    dst[0] = make_float4(gv[0],  gv[1],  gv[2],  gv[3]);
    dst[1] = make_float4(gv[4],  gv[5],  gv[6],  gv[7]);
    dst[2] = make_float4(gv[8],  gv[9],  gv[10], gv[11]);
    dst[3] = make_float4(gv[12], gv[13], gv[14], 0.0f);
}

// ---------------------------------------------------------------------------
// Kernel 2: 3 stacked GRU layers + output projection, fused single scan.
// Grid: 16 blocks x 64 threads (1 wave). 8 lanes per batch element; lane
// j (0..4) owns h_j and computes gates r_j, z_j, n_j for all 3 layers.
// h broadcast to the 8-lane group via 5 independent ds_bpermute (constant
// addresses, hoisted). Layers chained in-register within one t-step.
// ---------------------------------------------------------------------------

// tree-reassociated dot-5 + bias: dep chain ~3 ops
#define DOT5(w, x, bias) ({                         \
    float _m1 = fmaf((w)[0], (x)[0], (bias));       \
    float _m2 = (w)[1] * (x)[1];                    \
    float _m3 = fmaf((w)[2], (x)[2], _m2);          \
    float _m4 = (w)[3] * (x)[3];                    \
    float _m5 = fmaf((w)[4], (x)[4], _m4);          \
    (_m1 + _m3) + _m5; })

// one GRU layer update for the h_j owned by this lane, then broadcast
#define GRU_LAYER(hj, hb, gr, gz, gn, whr, whz, whn, bhr, bhz, bhn) do {      \
    const float _ghr = DOT5(whr, hb, bhr);                                    \
    const float _ghz = DOT5(whz, hb, bhz);                                    \
    const float _ghn = DOT5(whn, hb, bhn);                                    \
    const float _r = fast_sigmoid((gr) + _ghr);                               \
    const float _z = fast_sigmoid((gz) + _ghz);                               \
    const float _n = fast_tanh((gn) + _r * _ghn);                             \
    hj = (1.0f - _z) * _n + _z * hj;                                          \
    const int _hi = __float_as_int(hj);                                       \
    hb[0] = __int_as_float(__builtin_amdgcn_ds_bpermute(bpa0, _hi));          \
    hb[1] = __int_as_float(__builtin_amdgcn_ds_bpermute(bpa1, _hi));          \
    hb[2] = __int_as_float(__builtin_amdgcn_ds_bpermute(bpa2, _hi));          \
    hb[3] = __int_as_float(__builtin_amdgcn_ds_bpermute(bpa3, _hi));          \
    hb[4] = __int_as_float(__builtin_amdgcn_ds_bpermute(bpa4, _hi));          \
} while (0)

__global__ __launch_bounds__(64) void gru_kernel(
    const float* __restrict__ gi0,
    const float* __restrict__ whh0, const float* __restrict__ bhh0,
    const float* __restrict__ wih1, const float* __restrict__ whh1,
    const float* __restrict__ bih1, const float* __restrict__ bhh1,
    const float* __restrict__ wih2, const float* __restrict__ whh2,
    const float* __restrict__ bih2, const float* __restrict__ bhh2,
    const float* __restrict__ Wout, const float* __restrict__ bout,
    float* __restrict__ out)
{
    const int lane = threadIdx.x & 63;
    const int grp  = lane >> 3;              // 8 batch elems per wave
    const int j    = lane & 7;
    const int jc   = (j < GH) ? j : GH - 1;  // idle lanes 5..7 clamp
    const int b    = blockIdx.x * 8 + grp;

    // broadcast addresses (constant over the loop): lane (base+i)
    const int base = lane & ~7;
    const int bpa0 = (base + 0) << 2;
    const int bpa1 = (base + 1) << 2;
    const int bpa2 = (base + 2) << 2;
    const int bpa3 = (base + 3) << 2;
    const int bpa4 = (base + 4) << 2;

    // ---- per-lane weights: rows jc, jc+5, jc+10 of each (15 x ...) matrix --
    float whr0[GH], whz0[GH], whn0[GH];
    float wir1[GH], wiz1[GH], win1[GH], whr1[GH], whz1[GH], whn1[GH];
    float wir2[GH], wiz2[GH], win2[GH], whr2[GH], whz2[GH], whn2[GH];
    float wo[GH];
#pragma unroll
    for (int i = 0; i < GH; ++i) {
        whr0[i] = whh0[(jc     ) * GH + i];
        whz0[i] = whh0[(jc +  5) * GH + i];
        whn0[i] = whh0[(jc + 10) * GH + i];
        wir1[i] = wih1[(jc     ) * GH + i];
        wiz1[i] = wih1[(jc +  5) * GH + i];
        win1[i] = wih1[(jc + 10) * GH + i];
        whr1[i] = whh1[(jc     ) * GH + i];
        whz1[i] = whh1[(jc +  5) * GH + i];
        whn1[i] = whh1[(jc + 10) * GH + i];
        wir2[i] = wih2[(jc     ) * GH + i];
        wiz2[i] = wih2[(jc +  5) * GH + i];
        win2[i] = wih2[(jc + 10) * GH + i];
        whr2[i] = whh2[(jc     ) * GH + i];
        whz2[i] = whh2[(jc +  5) * GH + i];
        whn2[i] = whh2[(jc + 10) * GH + i];
        wo[i]   = Wout[i];
    }
    const float bhr0 = bhh0[jc], bhz0 = bhh0[jc + 5], bhn0 = bhh0[jc + 10];
    const float bir1 = bih1[jc], biz1 = bih1[jc + 5], bin1 = bih1[jc + 10];
    const float bhr1 = bhh1[jc], bhz1 = bhh1[jc + 5], bhn1 = bhh1[jc + 10];
    const float bir2 = bih2[jc], biz2 = bih2[jc + 5], bin2 = bih2[jc + 10];
    const float bhr2 = bhh2[jc], bhz2 = bhh2[jc + 5], bhn2 = bhh2[jc + 10];
    const float bo   = bout[0];

    // ---- state ----
    float h0j = 0.f, h1j = 0.f, h2j = 0.f;
    float hb0[GH] = {0, 0, 0, 0, 0};
    float hb1[GH] = {0, 0, 0, 0, 0};
    float hb2[GH] = {0, 0, 0, 0, 0};

    // ---- gi0 prefetch, depth 2 (covers cross-XCD first-touch latency) ----
    const float* gp0 = gi0 + ((size_t)b) * 16;
    float p0r = gp0[jc], p0z = gp0[jc + 5], p0n = gp0[jc + 10];
    const float* gp1 = gi0 + ((size_t)(B_DIM + b)) * 16;
    float p1r = gp1[jc], p1z = gp1[jc + 5], p1n = gp1[jc + 10];

    for (int t = 0; t < T_DIM; ++t) {
        const float g0r = p0r, g0z = p0z, g0n = p0n;
        p0r = p1r; p0z = p1z; p0n = p1n;
        if (t + 2 < T_DIM) {
            const float* gp = gi0 + ((size_t)((t + 2) * B_DIM + b)) * 16;
            p1r = gp[jc]; p1z = gp[jc + 5]; p1n = gp[jc + 10];
        }

        // layer 0 (input gates precomputed)
        GRU_LAYER(h0j, hb0, g0r, g0z, g0n, whr0, whz0, whn0, bhr0, bhz0, bhn0);

        // layer 1
        {
            const float g1r = DOT5(wir1, hb0, bir1);
            const float g1z = DOT5(wiz1, hb0, biz1);
            const float g1n = DOT5(win1, hb0, bin1);
            GRU_LAYER(h1j, hb1, g1r, g1z, g1n, whr1, whz1, whn1, bhr1, bhz1, bhn1);
        }

        // layer 2
        {
            const float g2r = DOT5(wir2, hb1, bir2);
            const float g2z = DOT5(wiz2, hb1, biz2);
            const float g2n = DOT5(win2, hb1, bin2);
            GRU_LAYER(h2j, hb2, g2r, g2z, g2n, whr2, whz2, whn2, bhr2, bhz2, bhn2);
        }

        // output projection (lane 0 of each group)
        if (j == 0)
            out[t * B_DIM + b] = DOT5(wo, hb2, bo);
    }
}

// ---------------------------------------------------------------------------
extern "C" void kernel_launch(void* const* d_in, const int* in_sizes, int n_in,
                              void* d_out, int out_size, void* d_ws, size_t ws_size,
                              hipStream_t stream)
{
    (void)in_sizes; (void)n_in; (void)out_size; (void)ws_size;

    const float* X    = (const float*)d_in[0];
    const float* W1   = (const float*)d_in[1];
    const float* b1   = (const float*)d_in[2];
    const float* W2   = (const float*)d_in[3];
    const float* b2   = (const float*)d_in[4];
    const float* W3   = (const float*)d_in[5];
    const float* b3   = (const float*)d_in[6];
    const float* wih0 = (const float*)d_in[7];
    const float* whh0 = (const float*)d_in[8];
    const float* bih0 = (const float*)d_in[9];
    const float* bhh0 = (const float*)d_in[10];
    const float* wih1 = (const float*)d_in[11];
    const float* whh1 = (const float*)d_in[12];
    const float* bih1 = (const float*)d_in[13];
    const float* bhh1 = (const float*)d_in[14];
    const float* wih2 = (const float*)d_in[15];
    const float* whh2 = (const float*)d_in[16];
    const float* bih2 = (const float*)d_in[17];
    const float* bhh2 = (const float*)d_in[18];
    const float* Wout = (const float*)d_in[19];
    const float* bout = (const float*)d_in[20];

    ushort* Wp  = (ushort*)d_ws;                       // 400 frags * 1 KB = 400 KB
    float*  gi0 = (float*)((char*)d_ws + 524288);      // (32768, 16) fp32 = 2 MB

    pack_w1_kernel<<<NSTEP, 256, 0, stream>>>(W1, Wp);
    mlp_kernel<<<512, 256, 0, stream>>>(X, Wp, b1, W2, b2, W3, b3, wih0, bih0, gi0);
    gru_kernel<<<16, 64, 0, stream>>>(gi0, whh0, bhh0,
                                      wih1, whh1, bih1, bhh1,
                                      wih2, whh2, bih2, bhh2,
                                      Wout, bout, (float*)d_out);
}

// Round 5
// 275.926 us; speedup vs baseline: 1.0580x; 1.0580x over previous
//
#include <hip/hip_runtime.h>
#include <hip/hip_bf16.h>

// ---------------------------------------------------------------------------
// RnnGruModel: MLP (1600->60->15->10) fused with GRU-layer0 input-gate
// precompute, then 3 stacked GRU layers (H=5) + output projection.
// X@W1^T done in bf16 MFMA with hi/lo split (3 products) -> ~fp32 accuracy.
// GRU: layer-pipelined (systolic) scan. Lane quad = 1 batch; sub-lane s runs
// layer s (s=0,1,2) skewed by s timesteps; sub-lane 3 = output projection.
// Hand-off via DPP quad_perm (VALU, no LDS) -- no DS ops in the chain.
// Layouts: X (T,B,F) row-major, row r = t*128 + b.  Output (T,1,B): t*128+b.
// ---------------------------------------------------------------------------

#define T_DIM 256
#define B_DIM 128
#define F_DIM 1600
#define H1_DIM 60
#define H2_DIM 15
#define H3_DIM 10
#define GH 5
#define NSTEP 50          // K-steps of 32 (1600/32)

typedef __attribute__((ext_vector_type(8))) short bf16x8;   // MFMA A/B frag (4 VGPRs)
typedef __attribute__((ext_vector_type(4))) float f32x4;    // MFMA C/D frag
typedef __attribute__((ext_vector_type(2))) float f32x2;    // packed fp32 (v_pk_*)

__device__ __forceinline__ float fast_tanh(float x) {
    float e = __expf(2.0f * x);
    return 1.0f - __fdividef(2.0f, e + 1.0f);   // safe at +-inf
}
__device__ __forceinline__ float fast_sigmoid(float x) {
    return __fdividef(1.0f, 1.0f + __expf(-x)); // safe at +-inf
}
__device__ __forceinline__ ushort f2bf_rn(float x) {        // round-to-nearest bf16
    uint u = __float_as_uint(x);
    u += 0x7fffu + ((u >> 16) & 1u);
    return (ushort)(u >> 16);
}
// receive a value from lane-1 within the quad (quad_perm [3,0,1,2] = 0x93)
__device__ __forceinline__ float quad_prev(float v) {
    return __int_as_float(__builtin_amdgcn_mov_dpp(__float_as_int(v), 0x93, 0xf, 0xf, false));
}

// ---------------------------------------------------------------------------
// Kernel 0: pack W1 (60x1600 fp32, zero-padded to 64 rows) into frag-ordered
// bf16 hi/lo pairs (unchanged, verified).
// ---------------------------------------------------------------------------
__global__ __launch_bounds__(256) void pack_w1_kernel(
    const float* __restrict__ W1, ushort* __restrict__ Wp)
{
    const int s  = blockIdx.x;       // 0..49
    const int t  = threadIdx.x;
    const int nf = t >> 6;
    const int l  = t & 63;
    const int n  = nf * 16 + (l & 15);
    const int g  = l >> 4;

    ushort hi[8], lo[8];
#pragma unroll
    for (int j = 0; j < 8; ++j) {
        const int k = s * 32 + g * 8 + j;
        const float v = (n < H1_DIM) ? W1[n * F_DIM + k] : 0.0f;
        const ushort h = f2bf_rn(v);
        const float hf = __uint_as_float(((uint)h) << 16);
        const float r  = v - hf;                       // exact
        hi[j] = h;
        lo[j] = (ushort)(__float_as_uint(r) >> 16);    // truncate: |err| ~ 2^-17 |v|
    }
    ushort* dst = Wp + ((size_t)(s * 8 + nf * 2)) * 512 + l * 8;
#pragma unroll
    for (int j = 0; j < 8; ++j) dst[j] = hi[j];
#pragma unroll
    for (int j = 0; j < 8; ++j) dst[512 + j] = lo[j];
}

// ---------------------------------------------------------------------------
// Kernel 1: per-row MLP + gi0 precompute, MFMA edition (unchanged, verified).
// ---------------------------------------------------------------------------
__global__ __launch_bounds__(256) void mlp_kernel(
    const float* __restrict__ X,
    const ushort* __restrict__ Wp,
    const float* __restrict__ b1,
    const float* __restrict__ W2, const float* __restrict__ b2,
    const float* __restrict__ W3, const float* __restrict__ b3,
    const float* __restrict__ wih0, const float* __restrict__ bih0,
    float* __restrict__ gi0)
{
    __shared__ float red[4 * 4096];   // 64 KB: per-wave 64x64 C partials

    const int tid  = threadIdx.x;
    const int l    = tid & 63;
    const int w    = __builtin_amdgcn_readfirstlane(tid >> 6);
    const int lm   = l & 15;          // A-row / B-col lane index
    const int g    = l >> 4;          // k-slot group
    const int row0 = blockIdx.x * 64;

    f32x4 acc[4][4];
#pragma unroll
    for (int mf = 0; mf < 4; ++mf)
#pragma unroll
        for (int nf = 0; nf < 4; ++nf)
            acc[mf][nf] = (f32x4){0.f, 0.f, 0.f, 0.f};

    const int s0 = (w * NSTEP) >> 2;        // 0,12,25,37
    const int s1 = ((w + 1) * NSTEP) >> 2;  // 12,25,37,50

    for (int s = s0; s < s1; ++s) {
        bf16x8 bh[4], bl[4];
        const ushort* wp_s = Wp + (size_t)s * 4096 + l * 8;
#pragma unroll
        for (int nf = 0; nf < 4; ++nf) {
            bh[nf] = *(const bf16x8*)(wp_s + (nf * 2 + 0) * 512);
            bl[nf] = *(const bf16x8*)(wp_s + (nf * 2 + 1) * 512);
        }
        bf16x8 a_hi[4], a_lo[4];
#pragma unroll
        for (int mf = 0; mf < 4; ++mf) {
            const float* ap = X + (size_t)(row0 + mf * 16 + lm) * F_DIM + s * 32 + g * 8;
            const float4 x0 = *(const float4*)ap;
            const float4 x1 = *(const float4*)(ap + 4);
            const float xs8[8] = {x0.x, x0.y, x0.z, x0.w, x1.x, x1.y, x1.z, x1.w};
            bf16x8 ah, al;
#pragma unroll
            for (int j = 0; j < 8; ++j) {
                const float v = xs8[j];
                const uint  u = __float_as_uint(v);
                const uint uh = (u + 0x7fffu + ((u >> 16) & 1u)) & 0xffff0000u;
                const float hf = __uint_as_float(uh);
                const float r  = v - hf;               // exact
                ah[j] = (short)(uh >> 16);
                al[j] = (short)(__float_as_uint(r) >> 16);
            }
            a_hi[mf] = ah; a_lo[mf] = al;
        }
#pragma unroll
        for (int mf = 0; mf < 4; ++mf)
#pragma unroll
            for (int nf = 0; nf < 4; ++nf) {
                f32x4 c = acc[mf][nf];
                c = __builtin_amdgcn_mfma_f32_16x16x32_bf16(a_lo[mf], bh[nf], c, 0, 0, 0);
                c = __builtin_amdgcn_mfma_f32_16x16x32_bf16(a_hi[mf], bl[nf], c, 0, 0, 0);
                c = __builtin_amdgcn_mfma_f32_16x16x32_bf16(a_hi[mf], bh[nf], c, 0, 0, 0);
                acc[mf][nf] = c;
            }
    }

    float* myred = red + w * 4096;
#pragma unroll
    for (int mf = 0; mf < 4; ++mf)
#pragma unroll
        for (int nf = 0; nf < 4; ++nf)
#pragma unroll
            for (int q = 0; q < 4; ++q)
                myred[(mf * 16 + g * 4 + q) * 64 + nf * 16 + lm] = acc[mf][nf][q];
    __syncthreads();

    float rsum[16];
#pragma unroll
    for (int i = 0; i < 16; ++i) {
        const int p = tid + 256 * i;
        rsum[i] = red[p] + red[4096 + p] + red[8192 + p] + red[12288 + p];
    }
    __syncthreads();
    float* redp = red + 8192;              // 64 x 65 padded
#pragma unroll
    for (int i = 0; i < 16; ++i) {
        const int p = tid + 256 * i;
        redp[(p >> 6) * 65 + (p & 63)] = rsum[i];
    }
    __syncthreads();
    if (w != 0) return;

    float h1v[H1_DIM];
#pragma unroll
    for (int o = 0; o < H1_DIM; ++o)
        h1v[o] = fast_tanh(redp[l * 65 + o] + b1[o]);

    float h2v[H2_DIM];
#pragma unroll
    for (int j = 0; j < H2_DIM; ++j) {
        float sacc = b2[j];
#pragma unroll
        for (int o = 0; o < H1_DIM; ++o) sacc += W2[j * H1_DIM + o] * h1v[o];
        h2v[j] = fast_tanh(sacc);
    }

    float h3v[H3_DIM];
#pragma unroll
    for (int m = 0; m < H3_DIM; ++m) {
        float sacc = b3[m];
#pragma unroll
        for (int j = 0; j < H2_DIM; ++j) sacc += W3[m * H2_DIM + j] * h2v[j];
        h3v[m] = sacc;
    }

    float gv[15];
#pragma unroll
    for (int q = 0; q < 15; ++q) {
        float sacc = bih0[q];
#pragma unroll
        for (int m = 0; m < H3_DIM; ++m) sacc += wih0[q * H3_DIM + m] * h3v[m];
        gv[q] = sacc;
    }

    const int row = row0 + l;
    float4* dst = (float4*)(gi0 + (size_t)row * 16);
    dst[0] = make_float4(gv[0],  gv[1],  gv[2],  gv[3]);
    dst[1] = make_float4(gv[4],  gv[5],  gv[6],  gv[7]);
    dst[2] = make_float4(gv[8],  gv[9],  gv[10], gv[11]);
    dst[3] = make_float4(gv[12], gv[13], gv[14], 0.0f);
}

// ---------------------------------------------------------------------------
// Kernel 2: layer-pipelined GRU + projection.
// Grid: 8 blocks x 64 threads. Lane quad = 1 batch (16 batches/wave).
// sub 0/1/2 = GRU layer, skewed: at wall-step s, sub computes t = s - sub.
// sub 3 = projection of h2 (uses the same uniform dot path, gate-0 row).
// h hand-off via quad_perm DPP. Idle weight slots are zero (uniform stream).
// r/z dots packed f32x2 over gate pairs (0,1)(2,3)(4,5)(6,7)(8,9).
// ---------------------------------------------------------------------------
__global__ __launch_bounds__(64, 1) void gru_kernel(
    const float* __restrict__ gi0,
    const float* __restrict__ whh0, const float* __restrict__ bhh0,
    const float* __restrict__ wih1, const float* __restrict__ whh1,
    const float* __restrict__ bih1, const float* __restrict__ bhh1,
    const float* __restrict__ wih2, const float* __restrict__ whh2,
    const float* __restrict__ bih2, const float* __restrict__ bhh2,
    const float* __restrict__ Wout, const float* __restrict__ bout,
    float* __restrict__ out)
{
    const int lane = threadIdx.x & 63;
    const int sub  = lane & 3;
    const int b    = blockIdx.x * 16 + (lane >> 2);

    // ---- per-lane weights (content differs per sub; stream is uniform) ----
    f32x2 wi_rz[5][5], wh_rz[5][5];   // [gate-pair][j]
    float wi_n[5][5],  wh_n[5][5];    // n-gates 10+i
    f32x2 b_rz[5];                    // folded bias (bi+bh); sub0: bh only
    float b_in[5], b_hn[5];

#pragma unroll
    for (int p = 0; p < 5; ++p) {
        b_rz[p] = (f32x2){0.f, 0.f};
#pragma unroll
        for (int j = 0; j < 5; ++j) {
            wi_rz[p][j] = (f32x2){0.f, 0.f};
            wh_rz[p][j] = (f32x2){0.f, 0.f};
        }
    }
#pragma unroll
    for (int i = 0; i < 5; ++i) {
        b_in[i] = 0.f; b_hn[i] = 0.f;
#pragma unroll
        for (int j = 0; j < 5; ++j) { wi_n[i][j] = 0.f; wh_n[i][j] = 0.f; }
    }

    if (sub == 0) {
#pragma unroll
        for (int p = 0; p < 5; ++p) {
            b_rz[p] = (f32x2){bhh0[2 * p], bhh0[2 * p + 1]};   // bi is inside gi0
#pragma unroll
            for (int j = 0; j < 5; ++j)
                wh_rz[p][j] = (f32x2){whh0[(2 * p) * GH + j], whh0[(2 * p + 1) * GH + j]};
        }
#pragma unroll
        for (int i = 0; i < 5; ++i) {
            b_hn[i] = bhh0[10 + i];
#pragma unroll
            for (int j = 0; j < 5; ++j) wh_n[i][j] = whh0[(10 + i) * GH + j];
        }
    } else if (sub == 1 || sub == 2) {
        const float* wi = (sub == 1) ? wih1 : wih2;
        const float* wh = (sub == 1) ? whh1 : whh2;
        const float* bi = (sub == 1) ? bih1 : bih2;
        const float* bh = (sub == 1) ? bhh1 : bhh2;
#pragma unroll
        for (int p = 0; p < 5; ++p) {
            b_rz[p] = (f32x2){bi[2 * p] + bh[2 * p], bi[2 * p + 1] + bh[2 * p + 1]};
#pragma unroll
            for (int j = 0; j < 5; ++j) {
                wi_rz[p][j] = (f32x2){wi[(2 * p) * GH + j], wi[(2 * p + 1) * GH + j]};
                wh_rz[p][j] = (f32x2){wh[(2 * p) * GH + j], wh[(2 * p + 1) * GH + j]};
            }
        }
#pragma unroll
        for (int i = 0; i < 5; ++i) {
            b_in[i] = bi[10 + i]; b_hn[i] = bh[10 + i];
#pragma unroll
            for (int j = 0; j < 5; ++j) {
                wi_n[i][j] = wi[(10 + i) * GH + j];
                wh_n[i][j] = wh[(10 + i) * GH + j];
            }
        }
    } else {            // sub == 3: projection lives in gate 0 (lo of pair 0)
#pragma unroll
        for (int j = 0; j < 5; ++j) wi_rz[0][j].x = Wout[j];
        b_rz[0].x = bout[0];
    }

    // ---- state ----
    float h[GH] = {0.f, 0.f, 0.f, 0.f, 0.f};
    float pre[15];
#pragma unroll
    for (int i = 0; i < 15; ++i) pre[i] = 0.f;

    // prologue: sub0 loads gi0 row t=0 (masked lanes keep pre = 0 forever)
    if (sub == 0) {
        const float4* gp = (const float4*)(gi0 + (size_t)b * 16);
        const float4 A = gp[0], B4 = gp[1], C = gp[2], D = gp[3];
        pre[0] = A.x;  pre[1] = A.y;  pre[2]  = A.z;  pre[3]  = A.w;
        pre[4] = B4.x; pre[5] = B4.y; pre[6]  = B4.z; pre[7]  = B4.w;
        pre[8] = C.x;  pre[9] = C.y;  pre[10] = C.z;  pre[11] = C.w;
        pre[12] = D.x; pre[13] = D.y; pre[14] = D.z;
    }

    for (int s = 0; s < T_DIM + 3; ++s) {
        // receive x = previous sub-lane's h (their end-of-step s-1 value)
        float x[GH];
#pragma unroll
        for (int i = 0; i < GH; ++i) x[i] = quad_prev(h[i]);

        // start accumulators: pre (gi0 / 0) + folded bias
        f32x2 srz[5];
        float gin[5], ghn[5];
#pragma unroll
        for (int p = 0; p < 5; ++p)
            srz[p] = b_rz[p] + (f32x2){pre[2 * p], pre[2 * p + 1]};
#pragma unroll
        for (int i = 0; i < 5; ++i) { gin[i] = b_in[i] + pre[10 + i]; ghn[i] = b_hn[i]; }

        // prefetch next gi0 row (pre already consumed; ~full step of slack)
        if (sub == 0 && s + 1 < T_DIM) {
            const float4* gp = (const float4*)(gi0 + (size_t)((s + 1) * B_DIM + b) * 16);
            const float4 A = gp[0], B4 = gp[1], C = gp[2], D = gp[3];
            pre[0] = A.x;  pre[1] = A.y;  pre[2]  = A.z;  pre[3]  = A.w;
            pre[4] = B4.x; pre[5] = B4.y; pre[6]  = B4.z; pre[7]  = B4.w;
            pre[8] = C.x;  pre[9] = C.y;  pre[10] = C.z;  pre[11] = C.w;
            pre[12] = D.x; pre[13] = D.y; pre[14] = D.z;
        }

        // dots: srz += Wi_rz @ x + Wh_rz @ h (packed); gin/ghn scalar
#pragma unroll
        for (int j = 0; j < GH; ++j) {
            const f32x2 xs = (f32x2){x[j], x[j]};
            const f32x2 hs = (f32x2){h[j], h[j]};
#pragma unroll
            for (int p = 0; p < 5; ++p) {
                srz[p] = __builtin_elementwise_fma(wi_rz[p][j], xs, srz[p]);
                srz[p] = __builtin_elementwise_fma(wh_rz[p][j], hs, srz[p]);
            }
#pragma unroll
            for (int i = 0; i < 5; ++i) {
                gin[i] = fmaf(wi_n[i][j], x[j], gin[i]);
                ghn[i] = fmaf(wh_n[i][j], h[j], ghn[i]);
            }
        }

        // projection store (sub3: y = gate0 pre-activation)
        if (sub == 3 && (unsigned)(s - 3) < (unsigned)T_DIM)
            out[(s - 3) * B_DIM + b] = srz[0].x;

        // gates: r = sig(gates 0..4), z = sig(gates 5..9)
        const float r0 = fast_sigmoid(srz[0].x);
        const float r1 = fast_sigmoid(srz[0].y);
        const float r2 = fast_sigmoid(srz[1].x);
        const float r3 = fast_sigmoid(srz[1].y);
        const float r4 = fast_sigmoid(srz[2].x);
        const float z0 = fast_sigmoid(srz[2].y);
        const float z1 = fast_sigmoid(srz[3].x);
        const float z2 = fast_sigmoid(srz[3].y);
        const float z3 = fast_sigmoid(srz[4].x);
        const float z4 = fast_sigmoid(srz[4].y);
        const float rr[5] = {r0, r1, r2, r3, r4};
        const float zz[5] = {z0, z1, z2, z3, z4};

        // n and h update, masked by per-lane validity (t = s - sub in range)
        const bool valid = (unsigned)(s - sub) < (unsigned)T_DIM;
#pragma unroll
        for (int i = 0; i < 5; ++i) {
            const float n  = fast_tanh(fmaf(rr[i], ghn[i], gin[i]));
            const float hu = fmaf(zz[i], h[i] - n, n);    // (1-z)n + z h
            h[i] = valid ? hu : h[i];
        }
    }
}

// ---------------------------------------------------------------------------
extern "C" void kernel_launch(void* const* d_in, const int* in_sizes, int n_in,
                              void* d_out, int out_size, void* d_ws, size_t ws_size,
                              hipStream_t stream)
{
    (void)in_sizes; (void)n_in; (void)out_size; (void)ws_size;

    const float* X    = (const float*)d_in[0];
    const float* W1   = (const float*)d_in[1];
    const float* b1   = (const float*)d_in[2];
    const float* W2   = (const float*)d_in[3];
    const float* b2   = (const float*)d_in[4];
    const float* W3   = (const float*)d_in[5];
    const float* b3   = (const float*)d_in[6];
    const float* wih0 = (const float*)d_in[7];
    const float* whh0 = (const float*)d_in[8];
    const float* bih0 = (const float*)d_in[9];
    const float* bhh0 = (const float*)d_in[10];
    const float* wih1 = (const float*)d_in[11];
    const float* whh1 = (const float*)d_in[12];
    const float* bih1 = (const float*)d_in[13];
    const float* bhh1 = (const float*)d_in[14];
    const float* wih2 = (const float*)d_in[15];
    const float* whh2 = (const float*)d_in[16];
    const float* bih2 = (const float*)d_in[17];
    const float* bhh2 = (const float*)d_in[18];
    const float* Wout = (const float*)d_in[19];
    const float* bout = (const float*)d_in[20];

    ushort* Wp  = (ushort*)d_ws;                       // 400 frags * 1 KB = 400 KB
    float*  gi0 = (float*)((char*)d_ws + 524288);      // (32768, 16) fp32 = 2 MB

    pack_w1_kernel<<<NSTEP, 256, 0, stream>>>(W1, Wp);
    mlp_kernel<<<512, 256, 0, stream>>>(X, Wp, b1, W2, b2, W3, b3, wih0, bih0, gi0);
    gru_kernel<<<8, 64, 0, stream>>>(gi0, whh0, bhh0,
                                     wih1, whh1, bih1, bhh1,
                                     wih2, whh2, bih2, bhh2,
                                     Wout, bout, (float*)d_out);
}

// Round 6
// 263.246 us; speedup vs baseline: 1.1089x; 1.0482x over previous
//
#include <hip/hip_runtime.h>
#include <hip/hip_bf16.h>

// ---------------------------------------------------------------------------
// RnnGruModel: MLP (1600->60->15->10) fused with GRU-layer0 input-gate
// precompute, then 3 stacked GRU layers (H=5) + output projection.
// X@W1^T done in bf16 MFMA with hi/lo split (3 products) -> ~fp32 accuracy.
// GRU: layer-pipelined (systolic) scan, quad per batch, DPP hand-off.
// gi0 is staged into LDS by a dedicated producer wave (double-buffered,
// 32-step chunks) so the recurrence loop issues ZERO global loads.
// Layouts: X (T,B,F) row-major, row r = t*128 + b.  Output (T,1,B): t*128+b.
// ---------------------------------------------------------------------------

#define T_DIM 256
#define B_DIM 128
#define F_DIM 1600
#define H1_DIM 60
#define H2_DIM 15
#define H3_DIM 10
#define GH 5
#define NSTEP 50          // MLP K-steps of 32 (1600/32)
#define CT 32             // GRU LDS chunk: timesteps per buffer
#define NCH (T_DIM / CT)  // 8 chunks

typedef __attribute__((ext_vector_type(8))) short bf16x8;   // MFMA A/B frag (4 VGPRs)
typedef __attribute__((ext_vector_type(4))) float f32x4;    // MFMA C/D frag
typedef __attribute__((ext_vector_type(2))) float f32x2;    // packed fp32 (v_pk_*)

__device__ __forceinline__ float fast_tanh(float x) {
    float e = __expf(2.0f * x);
    return 1.0f - __fdividef(2.0f, e + 1.0f);   // safe at +-inf
}
__device__ __forceinline__ float fast_sigmoid(float x) {
    return __fdividef(1.0f, 1.0f + __expf(-x)); // safe at +-inf
}
__device__ __forceinline__ ushort f2bf_rn(float x) {        // round-to-nearest bf16
    uint u = __float_as_uint(x);
    u += 0x7fffu + ((u >> 16) & 1u);
    return (ushort)(u >> 16);
}
// receive a value from lane-1 within the quad (quad_perm [3,0,1,2] = 0x93)
__device__ __forceinline__ float quad_prev(float v) {
    return __int_as_float(__builtin_amdgcn_mov_dpp(__float_as_int(v), 0x93, 0xf, 0xf, false));
}

// ---------------------------------------------------------------------------
// Kernel 0: pack W1 (60x1600 fp32, zero-padded to 64 rows) into frag-ordered
// bf16 hi/lo pairs (unchanged, verified).
// ---------------------------------------------------------------------------
__global__ __launch_bounds__(256) void pack_w1_kernel(
    const float* __restrict__ W1, ushort* __restrict__ Wp)
{
    const int s  = blockIdx.x;       // 0..49
    const int t  = threadIdx.x;
    const int nf = t >> 6;
    const int l  = t & 63;
    const int n  = nf * 16 + (l & 15);
    const int g  = l >> 4;

    ushort hi[8], lo[8];
#pragma unroll
    for (int j = 0; j < 8; ++j) {
        const int k = s * 32 + g * 8 + j;
        const float v = (n < H1_DIM) ? W1[n * F_DIM + k] : 0.0f;
        const ushort h = f2bf_rn(v);
        const float hf = __uint_as_float(((uint)h) << 16);
        const float r  = v - hf;                       // exact
        hi[j] = h;
        lo[j] = (ushort)(__float_as_uint(r) >> 16);    // truncate: |err| ~ 2^-17 |v|
    }
    ushort* dst = Wp + ((size_t)(s * 8 + nf * 2)) * 512 + l * 8;
#pragma unroll
    for (int j = 0; j < 8; ++j) dst[j] = hi[j];
#pragma unroll
    for (int j = 0; j < 8; ++j) dst[512 + j] = lo[j];
}

// ---------------------------------------------------------------------------
// Kernel 1: per-row MLP + gi0 precompute, MFMA edition (unchanged, verified).
// ---------------------------------------------------------------------------
__global__ __launch_bounds__(256) void mlp_kernel(
    const float* __restrict__ X,
    const ushort* __restrict__ Wp,
    const float* __restrict__ b1,
    const float* __restrict__ W2, const float* __restrict__ b2,
    const float* __restrict__ W3, const float* __restrict__ b3,
    const float* __restrict__ wih0, const float* __restrict__ bih0,
    float* __restrict__ gi0)
{
    __shared__ float red[4 * 4096];   // 64 KB: per-wave 64x64 C partials

    const int tid  = threadIdx.x;
    const int l    = tid & 63;
    const int w    = __builtin_amdgcn_readfirstlane(tid >> 6);
    const int lm   = l & 15;          // A-row / B-col lane index
    const int g    = l >> 4;          // k-slot group
    const int row0 = blockIdx.x * 64;

    f32x4 acc[4][4];
#pragma unroll
    for (int mf = 0; mf < 4; ++mf)
#pragma unroll
        for (int nf = 0; nf < 4; ++nf)
            acc[mf][nf] = (f32x4){0.f, 0.f, 0.f, 0.f};

    const int s0 = (w * NSTEP) >> 2;        // 0,12,25,37
    const int s1 = ((w + 1) * NSTEP) >> 2;  // 12,25,37,50

    for (int s = s0; s < s1; ++s) {
        bf16x8 bh[4], bl[4];
        const ushort* wp_s = Wp + (size_t)s * 4096 + l * 8;
#pragma unroll
        for (int nf = 0; nf < 4; ++nf) {
            bh[nf] = *(const bf16x8*)(wp_s + (nf * 2 + 0) * 512);
            bl[nf] = *(const bf16x8*)(wp_s + (nf * 2 + 1) * 512);
        }
        bf16x8 a_hi[4], a_lo[4];
#pragma unroll
        for (int mf = 0; mf < 4; ++mf) {
            const float* ap = X + (size_t)(row0 + mf * 16 + lm) * F_DIM + s * 32 + g * 8;
            const float4 x0 = *(const float4*)ap;
            const float4 x1 = *(const float4*)(ap + 4);
            const float xs8[8] = {x0.x, x0.y, x0.z, x0.w, x1.x, x1.y, x1.z, x1.w};
            bf16x8 ah, al;
#pragma unroll
            for (int j = 0; j < 8; ++j) {
                const float v = xs8[j];
                const uint  u = __float_as_uint(v);
                const uint uh = (u + 0x7fffu + ((u >> 16) & 1u)) & 0xffff0000u;
                const float hf = __uint_as_float(uh);
                const float r  = v - hf;               // exact
                ah[j] = (short)(uh >> 16);
                al[j] = (short)(__float_as_uint(r) >> 16);
            }
            a_hi[mf] = ah; a_lo[mf] = al;
        }
#pragma unroll
        for (int mf = 0; mf < 4; ++mf)
#pragma unroll
            for (int nf = 0; nf < 4; ++nf) {
                f32x4 c = acc[mf][nf];
                c = __builtin_amdgcn_mfma_f32_16x16x32_bf16(a_lo[mf], bh[nf], c, 0, 0, 0);
                c = __builtin_amdgcn_mfma_f32_16x16x32_bf16(a_hi[mf], bl[nf], c, 0, 0, 0);
                c = __builtin_amdgcn_mfma_f32_16x16x32_bf16(a_hi[mf], bh[nf], c, 0, 0, 0);
                acc[mf][nf] = c;
            }
    }

    float* myred = red + w * 4096;
#pragma unroll
    for (int mf = 0; mf < 4; ++mf)
#pragma unroll
        for (int nf = 0; nf < 4; ++nf)
#pragma unroll
            for (int q = 0; q < 4; ++q)
                myred[(mf * 16 + g * 4 + q) * 64 + nf * 16 + lm] = acc[mf][nf][q];
    __syncthreads();

    float rsum[16];
#pragma unroll
    for (int i = 0; i < 16; ++i) {
        const int p = tid + 256 * i;
        rsum[i] = red[p] + red[4096 + p] + red[8192 + p] + red[12288 + p];
    }
    __syncthreads();
    float* redp = red + 8192;              // 64 x 65 padded
#pragma unroll
    for (int i = 0; i < 16; ++i) {
        const int p = tid + 256 * i;
        redp[(p >> 6) * 65 + (p & 63)] = rsum[i];
    }
    __syncthreads();
    if (w != 0) return;

    float h1v[H1_DIM];
#pragma unroll
    for (int o = 0; o < H1_DIM; ++o)
        h1v[o] = fast_tanh(redp[l * 65 + o] + b1[o]);

    float h2v[H2_DIM];
#pragma unroll
    for (int j = 0; j < H2_DIM; ++j) {
        float sacc = b2[j];
#pragma unroll
        for (int o = 0; o < H1_DIM; ++o) sacc += W2[j * H1_DIM + o] * h1v[o];
        h2v[j] = fast_tanh(sacc);
    }

    float h3v[H3_DIM];
#pragma unroll
    for (int m = 0; m < H3_DIM; ++m) {
        float sacc = b3[m];
#pragma unroll
        for (int j = 0; j < H2_DIM; ++j) sacc += W3[m * H2_DIM + j] * h2v[j];
        h3v[m] = sacc;
    }

    float gv[15];
#pragma unroll
    for (int q = 0; q < 15; ++q) {
        float sacc = bih0[q];
#pragma unroll
        for (int m = 0; m < H3_DIM; ++m) sacc += wih0[q * H3_DIM + m] * h3v[m];
        gv[q] = sacc;
    }

    const int row = row0 + l;
    float4* dst = (float4*)(gi0 + (size_t)row * 16);
    dst[0] = make_float4(gv[0],  gv[1],  gv[2],  gv[3]);
    dst[1] = make_float4(gv[4],  gv[5],  gv[6],  gv[7]);
    dst[2] = make_float4(gv[8],  gv[9],  gv[10], gv[11]);
    dst[3] = make_float4(gv[12], gv[13], gv[14], 0.0f);
}

// ---------------------------------------------------------------------------
// Kernel 2: layer-pipelined GRU + projection, producer/consumer edition.
// Grid: 8 blocks x 128 threads. Wave 0 = compute (16 batches, quad each);
// wave 1 = producer staging gi0 chunks (CT=32 steps) into double-buffered
// LDS. Recurrence loop has ZERO global loads; pre comes from LDS with a
// 1-step register prefetch. Barrier once per 32 steps.
// ---------------------------------------------------------------------------

#define LOADPRE(PTR) do {                                                   \
    const float4* _pp = (const float4*)(PTR);                               \
    const float4 _A = _pp[0], _B = _pp[1], _C = _pp[2], _D = _pp[3];        \
    pre[0]  = _A.x; pre[1]  = _A.y; pre[2]  = _A.z; pre[3]  = _A.w;         \
    pre[4]  = _B.x; pre[5]  = _B.y; pre[6]  = _B.z; pre[7]  = _B.w;         \
    pre[8]  = _C.x; pre[9]  = _C.y; pre[10] = _C.z; pre[11] = _C.w;         \
    pre[12] = _D.x; pre[13] = _D.y; pre[14] = _D.z;                         \
} while (0)

#define GSTEP(S, PREF) do {                                                 \
    float x[GH];                                                            \
    _Pragma("unroll") for (int i = 0; i < GH; ++i) x[i] = quad_prev(h[i]);  \
    f32x2 srz[5]; float gin[5], ghn[5];                                     \
    _Pragma("unroll") for (int p = 0; p < 5; ++p)                           \
        srz[p] = b_rz[p] + (f32x2){pre[2 * p], pre[2 * p + 1]};             \
    _Pragma("unroll") for (int i = 0; i < 5; ++i)                           \
        { gin[i] = b_in[i] + pre[10 + i]; ghn[i] = b_hn[i]; }               \
    PREF                                                                    \
    _Pragma("unroll") for (int j = 0; j < GH; ++j) {                        \
        const f32x2 xs = (f32x2){x[j], x[j]};                               \
        const f32x2 hs = (f32x2){h[j], h[j]};                               \
        _Pragma("unroll") for (int p = 0; p < 5; ++p) {                     \
            srz[p] = __builtin_elementwise_fma(wi_rz[p][j], xs, srz[p]);    \
            srz[p] = __builtin_elementwise_fma(wh_rz[p][j], hs, srz[p]);    \
        }                                                                   \
        _Pragma("unroll") for (int i = 0; i < 5; ++i) {                     \
            gin[i] = fmaf(wi_n[i][j], x[j], gin[i]);                        \
            ghn[i] = fmaf(wh_n[i][j], h[j], ghn[i]);                        \
        }                                                                   \
    }                                                                       \
    if (sub == 3 && (unsigned)((S) - 3) < (unsigned)T_DIM)                  \
        out[((S) - 3) * B_DIM + b] = srz[0].x;                              \
    const float rr[5] = {fast_sigmoid(srz[0].x), fast_sigmoid(srz[0].y),    \
                         fast_sigmoid(srz[1].x), fast_sigmoid(srz[1].y),    \
                         fast_sigmoid(srz[2].x)};                           \
    const float zz[5] = {fast_sigmoid(srz[2].y), fast_sigmoid(srz[3].x),    \
                         fast_sigmoid(srz[3].y), fast_sigmoid(srz[4].x),    \
                         fast_sigmoid(srz[4].y)};                           \
    const bool valid = (unsigned)((S) - sub) < (unsigned)T_DIM;             \
    _Pragma("unroll") for (int i = 0; i < 5; ++i) {                         \
        const float n  = fast_tanh(fmaf(rr[i], ghn[i], gin[i]));            \
        const float hu = fmaf(zz[i], h[i] - n, n);                          \
        h[i] = valid ? hu : h[i];                                           \
    }                                                                       \
} while (0)

// producer: stage chunk C (rows C*CT .. C*CT+31) into gbuf[C&1], 8-deep loads
#define STAGE(C) do {                                                       \
    const int _cb = (C) & 1;                                                \
    _Pragma("unroll") for (int _h = 0; _h < 4; ++_h) {                      \
        float4 _v[8];                                                       \
        _Pragma("unroll") for (int _i = 0; _i < 8; ++_i) {                  \
            const int _tl = _h * 8 + _i;                                    \
            _v[_i] = *(const float4*)(gi0 +                                 \
                ((size_t)(((C) * CT + _tl) * B_DIM + b0 + bl)) * 16 + q * 4);\
        }                                                                   \
        _Pragma("unroll") for (int _i = 0; _i < 8; ++_i)                    \
            *(float4*)&gbuf[_cb][_h * 8 + _i][bl][q * 4] = _v[_i];          \
    }                                                                       \
} while (0)

__global__ __launch_bounds__(128, 1) void gru_kernel(
    const float* __restrict__ gi0,
    const float* __restrict__ whh0, const float* __restrict__ bhh0,
    const float* __restrict__ wih1, const float* __restrict__ whh1,
    const float* __restrict__ bih1, const float* __restrict__ bhh1,
    const float* __restrict__ wih2, const float* __restrict__ whh2,
    const float* __restrict__ bih2, const float* __restrict__ bhh2,
    const float* __restrict__ Wout, const float* __restrict__ bout,
    float* __restrict__ out)
{
    __shared__ float gbuf[2][CT][16][16];   // 64 KB double-buffered gi0 chunks

    const int tid  = threadIdx.x;
    const int w    = __builtin_amdgcn_readfirstlane(tid >> 6);
    const int lane = tid & 63;
    const int b0   = blockIdx.x * 16;

    if (w == 1) {
        // ---------------- producer wave ----------------
        const int bl = (lane >> 2) & 15;   // batch_local
        const int q  = lane & 3;           // float4 quarter of the 16-float row
        STAGE(0);
        __syncthreads();                   // chunk 0 visible
        for (int c = 0; c < NCH; ++c) {
            if (c + 1 < NCH) STAGE(c + 1);
            __syncthreads();               // publish chunk c+1; consumer done with c
        }
        return;
    }

    // ---------------- consumer wave (systolic GRU) ----------------
    const int sub = lane & 3;
    const int bb  = lane >> 2;             // batch_local
    const int b   = b0 + bb;

    // ---- per-lane weights (content differs per sub; stream is uniform) ----
    f32x2 wi_rz[5][5], wh_rz[5][5];   // [gate-pair][j]
    float wi_n[5][5],  wh_n[5][5];    // n-gates 10+i
    f32x2 b_rz[5];                    // folded bias (bi+bh); sub0: bh only
    float b_in[5], b_hn[5];

#pragma unroll
    for (int p = 0; p < 5; ++p) {
        b_rz[p] = (f32x2){0.f, 0.f};
#pragma unroll
        for (int j = 0; j < 5; ++j) {
            wi_rz[p][j] = (f32x2){0.f, 0.f};
            wh_rz[p][j] = (f32x2){0.f, 0.f};
        }
    }
#pragma unroll
    for (int i = 0; i < 5; ++i) {
        b_in[i] = 0.f; b_hn[i] = 0.f;
#pragma unroll
        for (int j = 0; j < 5; ++j) { wi_n[i][j] = 0.f; wh_n[i][j] = 0.f; }
    }

    if (sub == 0) {
#pragma unroll
        for (int p = 0; p < 5; ++p) {
            b_rz[p] = (f32x2){bhh0[2 * p], bhh0[2 * p + 1]};   // bi is inside gi0
#pragma unroll
            for (int j = 0; j < 5; ++j)
                wh_rz[p][j] = (f32x2){whh0[(2 * p) * GH + j], whh0[(2 * p + 1) * GH + j]};
        }
#pragma unroll
        for (int i = 0; i < 5; ++i) {
            b_hn[i] = bhh0[10 + i];
#pragma unroll
            for (int j = 0; j < 5; ++j) wh_n[i][j] = whh0[(10 + i) * GH + j];
        }
    } else if (sub == 1 || sub == 2) {
        const float* wi = (sub == 1) ? wih1 : wih2;
        const float* wh = (sub == 1) ? whh1 : whh2;
        const float* bi = (sub == 1) ? bih1 : bih2;
        const float* bh = (sub == 1) ? bhh1 : bhh2;
#pragma unroll
        for (int p = 0; p < 5; ++p) {
            b_rz[p] = (f32x2){bi[2 * p] + bh[2 * p], bi[2 * p + 1] + bh[2 * p + 1]};
#pragma unroll
            for (int j = 0; j < 5; ++j) {
                wi_rz[p][j] = (f32x2){wi[(2 * p) * GH + j], wi[(2 * p + 1) * GH + j]};
                wh_rz[p][j] = (f32x2){wh[(2 * p) * GH + j], wh[(2 * p + 1) * GH + j]};
            }
        }
#pragma unroll
        for (int i = 0; i < 5; ++i) {
            b_in[i] = bi[10 + i]; b_hn[i] = bh[10 + i];
#pragma unroll
            for (int j = 0; j < 5; ++j) {
                wi_n[i][j] = wi[(10 + i) * GH + j];
                wh_n[i][j] = wh[(10 + i) * GH + j];
            }
        }
    } else {            // sub == 3: projection lives in gate 0 (lo of pair 0)
#pragma unroll
        for (int j = 0; j < 5; ++j) wi_rz[0][j].x = Wout[j];
        b_rz[0].x = bout[0];
    }

    // ---- state ----
    float h[GH] = {0.f, 0.f, 0.f, 0.f, 0.f};
    float pre[15];
#pragma unroll
    for (int i = 0; i < 15; ++i) pre[i] = 0.f;

    __syncthreads();                       // chunk 0 staged
    if (sub == 0) { LOADPRE(&gbuf[0][0][bb][0]); }

    for (int c = 0; c < NCH; ++c) {
        const int cb = c & 1;
        for (int tl = 0; tl < CT; ++tl) {
            const int s = c * CT + tl;
            GSTEP(s,
                if (sub == 0 && tl + 1 < CT) { LOADPRE(&gbuf[cb][tl + 1][bb][0]); }
            );
        }
        __syncthreads();                   // chunk c done; chunk c+1 published
        if (c + 1 < NCH && sub == 0) { LOADPRE(&gbuf[(c + 1) & 1][0][bb][0]); }
    }

    // drain: 3 wall steps flush the layer pipeline (pre is stale but masked)
    for (int s = T_DIM; s < T_DIM + 3; ++s) {
        GSTEP(s, ;);
    }
}

// ---------------------------------------------------------------------------
extern "C" void kernel_launch(void* const* d_in, const int* in_sizes, int n_in,
                              void* d_out, int out_size, void* d_ws, size_t ws_size,
                              hipStream_t stream)
{
    (void)in_sizes; (void)n_in; (void)out_size; (void)ws_size;

    const float* X    = (const float*)d_in[0];
    const float* W1   = (const float*)d_in[1];
    const float* b1   = (const float*)d_in[2];
    const float* W2   = (const float*)d_in[3];
    const float* b2   = (const float*)d_in[4];
    const float* W3   = (const float*)d_in[5];
    const float* b3   = (const float*)d_in[6];
    const float* wih0 = (const float*)d_in[7];
    const float* whh0 = (const float*)d_in[8];
    const float* bih0 = (const float*)d_in[9];
    const float* bhh0 = (const float*)d_in[10];
    const float* wih1 = (const float*)d_in[11];
    const float* whh1 = (const float*)d_in[12];
    const float* bih1 = (const float*)d_in[13];
    const float* bhh1 = (const float*)d_in[14];
    const float* wih2 = (const float*)d_in[15];
    const float* whh2 = (const float*)d_in[16];
    const float* bih2 = (const float*)d_in[17];
    const float* bhh2 = (const float*)d_in[18];
    const float* Wout = (const float*)d_in[19];
    const float* bout = (const float*)d_in[20];

    ushort* Wp  = (ushort*)d_ws;                       // 400 frags * 1 KB = 400 KB
    float*  gi0 = (float*)((char*)d_ws + 524288);      // (32768, 16) fp32 = 2 MB

    pack_w1_kernel<<<NSTEP, 256, 0, stream>>>(W1, Wp);
    mlp_kernel<<<512, 256, 0, stream>>>(X, Wp, b1, W2, b2, W3, b3, wih0, bih0, gi0);
    gru_kernel<<<8, 128, 0, stream>>>(gi0, whh0, bhh0,
                                      wih1, whh1, bih1, bhh1,
                                      wih2, whh2, bih2, bhh2,
                                      Wout, bout, (float*)d_out);
}

// Round 8
// 204.714 us; speedup vs baseline: 1.4260x; 1.2859x over previous
//
#include <hip/hip_runtime.h>
#include <hip/hip_bf16.h>

// ---------------------------------------------------------------------------
// RnnGruModel: MLP (1600->60->15->10) fused with GRU-layer0 input-gate
// precompute, then 3 stacked GRU layers (H=5) + output projection.
// X@W1^T done in bf16 MFMA with hi/lo split (3 products) -> ~fp32 accuracy.
// GRU: systolic layer pipeline. 16 lanes per batch = 4 quads:
//   quad l (l=0,1,2) = GRU layer l at t = s - l; quad 3 = projection.
//   qlane 0/1/2 of a layer-quad owns the r/z/n gates (5 each, ~50 wgt regs).
// ALL cross-lane traffic is DPP (quad_perm broadcasts + row_shr:4 hand-off);
// no LDS/global ops in the recurrence chain. gi0 staged by a producer wave.
// R7 bug fixed: hand-off is row_SHR:4 (lane i <- lane i-4), 0x114. row_shl
// moves data the other way (lane i <- lane i+4) and sent the pipeline
// backwards (projection read zeros -> output == bout, matching the observed
// absmax 1.54e-2 = max|Wout.h2|).
// Layouts: X (T,B,F) row-major, row r = t*128 + b.  Output (T,1,B): t*128+b.
// ---------------------------------------------------------------------------

#define T_DIM 256
#define B_DIM 128
#define F_DIM 1600
#define H1_DIM 60
#define H2_DIM 15
#define H3_DIM 10
#define GH 5
#define NSTEP 50          // MLP K-steps of 32 (1600/32)
#define CT 32             // GRU LDS chunk: timesteps per buffer
#define NCH (T_DIM / CT)  // 8 chunks

#define DPP_B0   0x00     // quad_perm [0,0,0,0]
#define DPP_B1   0x55     // quad_perm [1,1,1,1]
#define DPP_B2   0xAA     // quad_perm [2,2,2,2]
#define DPP_SHR4 0x114    // row_shr:4 (lane i <- lane i-4 within 16-lane row)

typedef __attribute__((ext_vector_type(8))) short bf16x8;   // MFMA A/B frag (4 VGPRs)
typedef __attribute__((ext_vector_type(4))) float f32x4;    // MFMA C/D frag

__device__ __forceinline__ float fast_tanh(float x) {
    float e = __expf(2.0f * x);
    return 1.0f - __fdividef(2.0f, e + 1.0f);   // safe at +-inf
}
__device__ __forceinline__ float fast_sigmoid(float x) {
    return __fdividef(1.0f, 1.0f + __expf(-x)); // safe at +-inf
}
__device__ __forceinline__ ushort f2bf_rn(float x) {        // round-to-nearest bf16
    uint u = __float_as_uint(x);
    u += 0x7fffu + ((u >> 16) & 1u);
    return (ushort)(u >> 16);
}
template <int CTRL>
__device__ __forceinline__ float dppf(float v) {
    return __int_as_float(
        __builtin_amdgcn_mov_dpp(__float_as_int(v), CTRL, 0xf, 0xf, true));
}

// ---------------------------------------------------------------------------
// Kernel 0: pack W1 (60x1600 fp32, zero-padded to 64 rows) into frag-ordered
// bf16 hi/lo pairs (unchanged, verified).
// ---------------------------------------------------------------------------
__global__ __launch_bounds__(256) void pack_w1_kernel(
    const float* __restrict__ W1, ushort* __restrict__ Wp)
{
    const int s  = blockIdx.x;       // 0..49
    const int t  = threadIdx.x;
    const int nf = t >> 6;
    const int l  = t & 63;
    const int n  = nf * 16 + (l & 15);
    const int g  = l >> 4;

    ushort hi[8], lo[8];
#pragma unroll
    for (int j = 0; j < 8; ++j) {
        const int k = s * 32 + g * 8 + j;
        const float v = (n < H1_DIM) ? W1[n * F_DIM + k] : 0.0f;
        const ushort h = f2bf_rn(v);
        const float hf = __uint_as_float(((uint)h) << 16);
        const float r  = v - hf;                       // exact
        hi[j] = h;
        lo[j] = (ushort)(__float_as_uint(r) >> 16);    // truncate: |err| ~ 2^-17 |v|
    }
    ushort* dst = Wp + ((size_t)(s * 8 + nf * 2)) * 512 + l * 8;
#pragma unroll
    for (int j = 0; j < 8; ++j) dst[j] = hi[j];
#pragma unroll
    for (int j = 0; j < 8; ++j) dst[512 + j] = lo[j];
}

// ---------------------------------------------------------------------------
// Kernel 1: per-row MLP + gi0 precompute, MFMA edition (unchanged, verified).
// ---------------------------------------------------------------------------
__global__ __launch_bounds__(256) void mlp_kernel(
    const float* __restrict__ X,
    const ushort* __restrict__ Wp,
    const float* __restrict__ b1,
    const float* __restrict__ W2, const float* __restrict__ b2,
    const float* __restrict__ W3, const float* __restrict__ b3,
    const float* __restrict__ wih0, const float* __restrict__ bih0,
    float* __restrict__ gi0)
{
    __shared__ float red[4 * 4096];   // 64 KB: per-wave 64x64 C partials

    const int tid  = threadIdx.x;
    const int l    = tid & 63;
    const int w    = __builtin_amdgcn_readfirstlane(tid >> 6);
    const int lm   = l & 15;          // A-row / B-col lane index
    const int g    = l >> 4;          // k-slot group
    const int row0 = blockIdx.x * 64;

    f32x4 acc[4][4];
#pragma unroll
    for (int mf = 0; mf < 4; ++mf)
#pragma unroll
        for (int nf = 0; nf < 4; ++nf)
            acc[mf][nf] = (f32x4){0.f, 0.f, 0.f, 0.f};

    const int s0 = (w * NSTEP) >> 2;        // 0,12,25,37
    const int s1 = ((w + 1) * NSTEP) >> 2;  // 12,25,37,50

    for (int s = s0; s < s1; ++s) {
        bf16x8 bh[4], bl[4];
        const ushort* wp_s = Wp + (size_t)s * 4096 + l * 8;
#pragma unroll
        for (int nf = 0; nf < 4; ++nf) {
            bh[nf] = *(const bf16x8*)(wp_s + (nf * 2 + 0) * 512);
            bl[nf] = *(const bf16x8*)(wp_s + (nf * 2 + 1) * 512);
        }
        bf16x8 a_hi[4], a_lo[4];
#pragma unroll
        for (int mf = 0; mf < 4; ++mf) {
            const float* ap = X + (size_t)(row0 + mf * 16 + lm) * F_DIM + s * 32 + g * 8;
            const float4 x0 = *(const float4*)ap;
            const float4 x1 = *(const float4*)(ap + 4);
            const float xs8[8] = {x0.x, x0.y, x0.z, x0.w, x1.x, x1.y, x1.z, x1.w};
            bf16x8 ah, al;
#pragma unroll
            for (int j = 0; j < 8; ++j) {
                const float v = xs8[j];
                const uint  u = __float_as_uint(v);
                const uint uh = (u + 0x7fffu + ((u >> 16) & 1u)) & 0xffff0000u;
                const float hf = __uint_as_float(uh);
                const float r  = v - hf;               // exact
                ah[j] = (short)(uh >> 16);
                al[j] = (short)(__float_as_uint(r) >> 16);
            }
            a_hi[mf] = ah; a_lo[mf] = al;
        }
#pragma unroll
        for (int mf = 0; mf < 4; ++mf)
#pragma unroll
            for (int nf = 0; nf < 4; ++nf) {
                f32x4 c = acc[mf][nf];
                c = __builtin_amdgcn_mfma_f32_16x16x32_bf16(a_lo[mf], bh[nf], c, 0, 0, 0);
                c = __builtin_amdgcn_mfma_f32_16x16x32_bf16(a_hi[mf], bl[nf], c, 0, 0, 0);
                c = __builtin_amdgcn_mfma_f32_16x16x32_bf16(a_hi[mf], bh[nf], c, 0, 0, 0);
                acc[mf][nf] = c;
            }
    }

    float* myred = red + w * 4096;
#pragma unroll
    for (int mf = 0; mf < 4; ++mf)
#pragma unroll
        for (int nf = 0; nf < 4; ++nf)
#pragma unroll
            for (int q = 0; q < 4; ++q)
                myred[(mf * 16 + g * 4 + q) * 64 + nf * 16 + lm] = acc[mf][nf][q];
    __syncthreads();

    float rsum[16];
#pragma unroll
    for (int i = 0; i < 16; ++i) {
        const int p = tid + 256 * i;
        rsum[i] = red[p] + red[4096 + p] + red[8192 + p] + red[12288 + p];
    }
    __syncthreads();
    float* redp = red + 8192;              // 64 x 65 padded
#pragma unroll
    for (int i = 0; i < 16; ++i) {
        const int p = tid + 256 * i;
        redp[(p >> 6) * 65 + (p & 63)] = rsum[i];
    }
    __syncthreads();
    if (w != 0) return;

    float h1v[H1_DIM];
#pragma unroll
    for (int o = 0; o < H1_DIM; ++o)
        h1v[o] = fast_tanh(redp[l * 65 + o] + b1[o]);

    float h2v[H2_DIM];
#pragma unroll
    for (int j = 0; j < H2_DIM; ++j) {
        float sacc = b2[j];
#pragma unroll
        for (int o = 0; o < H1_DIM; ++o) sacc += W2[j * H1_DIM + o] * h1v[o];
        h2v[j] = fast_tanh(sacc);
    }

    float h3v[H3_DIM];
#pragma unroll
    for (int m = 0; m < H3_DIM; ++m) {
        float sacc = b3[m];
#pragma unroll
        for (int j = 0; j < H2_DIM; ++j) sacc += W3[m * H2_DIM + j] * h2v[j];
        h3v[m] = sacc;
    }

    float gv[15];
#pragma unroll
    for (int q = 0; q < 15; ++q) {
        float sacc = bih0[q];
#pragma unroll
        for (int m = 0; m < H3_DIM; ++m) sacc += wih0[q * H3_DIM + m] * h3v[m];
        gv[q] = sacc;
    }

    const int row = row0 + l;
    float4* dst = (float4*)(gi0 + (size_t)row * 16);
    dst[0] = make_float4(gv[0],  gv[1],  gv[2],  gv[3]);
    dst[1] = make_float4(gv[4],  gv[5],  gv[6],  gv[7]);
    dst[2] = make_float4(gv[8],  gv[9],  gv[10], gv[11]);
    dst[3] = make_float4(gv[12], gv[13], gv[14], 0.0f);
}

// ---------------------------------------------------------------------------
// Kernel 2: systolic GRU, gate-split quads, DPP-only cross-lane.
// Grid: 32 blocks x 128 threads. Wave 0 = compute (4 batches x 16 lanes);
// wave 1 = producer staging gi0 chunks (CT=32) into double-buffered LDS.
// ---------------------------------------------------------------------------

// producer: stage chunk C into gbuf[C&1]; 512 float4 per chunk, 8 per lane
#define STAGE(C) do {                                                       \
    const int _cb = (C) & 1;                                                \
    float4 _v[8];                                                           \
    _Pragma("unroll") for (int _i = 0; _i < 8; ++_i) {                      \
        const int _f = lane + 64 * _i;                                      \
        const int _r = _f >> 2;                                             \
        _v[_i] = *(const float4*)(gi0 +                                     \
            ((size_t)(((C) * CT + (_r >> 2)) * B_DIM + b0 + (_r & 3))) * 16 \
            + (_f & 3) * 4);                                                \
    }                                                                       \
    _Pragma("unroll") for (int _i = 0; _i < 8; ++_i) {                      \
        const int _f = lane + 64 * _i;                                      \
        const int _r = _f >> 2;                                             \
        *(float4*)&gbuf[_cb][_r >> 2][_r & 3][(_f & 3) * 4] = _v[_i];       \
    }                                                                       \
} while (0)

#define PREF(CB, TL) do {                                                   \
    _Pragma("unroll") for (int _i = 0; _i < 5; ++_i)                        \
        pre[_i] = lptr[(CB) * cstr + (TL) * str + _i];                      \
} while (0)

#define GSTEP(S, PREFCODE) do {                                             \
    float x[5];                                                             \
    _Pragma("unroll") for (int _i = 0; _i < 5; ++_i)                        \
        x[_i] = dppf<DPP_SHR4>(h[_i]);      /* prev quad's h(s-1) */        \
    float aA[5], aB[5];                                                     \
    _Pragma("unroll") for (int _i = 0; _i < 5; ++_i) {                      \
        aA[_i] = bA[_i] + pre[_i];                                          \
        aB[_i] = bB[_i];                                                    \
    }                                                                       \
    PREFCODE                                                                \
    _Pragma("unroll") for (int _j = 0; _j < 5; ++_j) {                      \
        _Pragma("unroll") for (int _i = 0; _i < 5; ++_i) {                  \
            aA[_i] = fmaf(w1[_i][_j], x[_j], aA[_i]);                       \
            aB[_i] = fmaf(w2[_i][_j], h[_j], aB[_i]);                       \
        }                                                                   \
    }                                                                       \
    float sA[5];                                                            \
    _Pragma("unroll") for (int _i = 0; _i < 5; ++_i) sA[_i] = aA[_i] + aB[_i]; \
    if (gl == 12 && (unsigned)((S) - 3) < (unsigned)T_DIM)                  \
        out[((S) - 3) * B_DIM + b] = sA[0];   /* projection pre-activation */ \
    float rq[5], zq[5];                                                     \
    _Pragma("unroll") for (int _i = 0; _i < 5; ++_i) {                      \
        const float _sg = fast_sigmoid(sA[_i]);                             \
        rq[_i] = dppf<DPP_B0>(_sg);        /* r_i from qlane0 */            \
        zq[_i] = dppf<DPP_B1>(_sg);        /* z_i from qlane1 */            \
    }                                                                       \
    const bool _valid = (unsigned)((S) - quad) < (unsigned)T_DIM;           \
    _Pragma("unroll") for (int _i = 0; _i < 5; ++_i) {                      \
        const float _n  = fast_tanh(fmaf(rq[_i], aB[_i], aA[_i]));          \
        const float _hn = fmaf(zq[_i], h[_i] - _n, _n);                     \
        const float _hv = _valid ? _hn : h[_i];                             \
        h[_i] = dppf<DPP_B2>(_hv);         /* h_i from qlane2 (n-lane) */   \
    }                                                                       \
} while (0)

__global__ __launch_bounds__(128, 1) void gru_kernel(
    const float* __restrict__ gi0,
    const float* __restrict__ whh0, const float* __restrict__ bhh0,
    const float* __restrict__ wih1, const float* __restrict__ whh1,
    const float* __restrict__ bih1, const float* __restrict__ bhh1,
    const float* __restrict__ wih2, const float* __restrict__ whh2,
    const float* __restrict__ bih2, const float* __restrict__ bhh2,
    const float* __restrict__ Wout, const float* __restrict__ bout,
    float* __restrict__ out)
{
    __shared__ float gbuf[2][CT][4][16];   // 16 KB double-buffered gi0 chunks
    __shared__ float zrow[16];             // zero row for non-reader lanes

    const int tid  = threadIdx.x;
    const int w    = __builtin_amdgcn_readfirstlane(tid >> 6);
    const int lane = tid & 63;
    const int b0   = blockIdx.x * 4;

    if (w == 1) {
        // ---------------- producer wave ----------------
        if (lane < 16) zrow[lane] = 0.f;
        STAGE(0);
        __syncthreads();                   // chunk 0 + zrow visible
        for (int c = 0; c < NCH; ++c) {
            if (c + 1 < NCH) STAGE(c + 1);
            __syncthreads();               // publish chunk c+1; consumer done with c
        }
        return;
    }

    // ---------------- consumer wave ----------------
    const int grp   = lane >> 4;           // batch within wave (DPP row = batch)
    const int gl    = lane & 15;
    const int quad  = gl >> 2;             // 0,1,2 = layer; 3 = projection
    const int qlane = gl & 3;              // 0=r, 1=z, 2=n, 3=idle
    const int b     = b0 + grp;

    // ---- per-lane weights: 5 gate rows (r/z/n slice of one layer) ----------
    float w1[5][5], w2[5][5], bA[5], bB[5];
#pragma unroll
    for (int i = 0; i < 5; ++i) {
        bA[i] = 0.f; bB[i] = 0.f;
#pragma unroll
        for (int j = 0; j < 5; ++j) { w1[i][j] = 0.f; w2[i][j] = 0.f; }
    }
    if (quad == 0) {
        if (qlane < 3) {                   // L0: x-side comes via pre (gi0)
            const int r0 = qlane * 5;
#pragma unroll
            for (int i = 0; i < 5; ++i) {
                const int rr = r0 + i;
#pragma unroll
                for (int j = 0; j < 5; ++j) w2[i][j] = whh0[rr * GH + j];
                if (qlane == 2) bB[i] = bhh0[rr];  // ghn bias separate
                else            bA[i] = bhh0[rr];  // bi is inside gi0
            }
        }
    } else if (quad < 3) {
        const float* wi = (quad == 1) ? wih1 : wih2;
        const float* wh = (quad == 1) ? whh1 : whh2;
        const float* bi = (quad == 1) ? bih1 : bih2;
        const float* bh = (quad == 1) ? bhh1 : bhh2;
        if (qlane < 3) {
            const int r0 = qlane * 5;
#pragma unroll
            for (int i = 0; i < 5; ++i) {
                const int rr = r0 + i;
#pragma unroll
                for (int j = 0; j < 5; ++j) {
                    w1[i][j] = wi[rr * GH + j];
                    w2[i][j] = wh[rr * GH + j];
                }
                if (qlane == 2) { bA[i] = bi[rr]; bB[i] = bh[rr]; }
                else            { bA[i] = bi[rr] + bh[rr]; }
            }
        }
    } else if (qlane == 0) {               // projection: y = Wout.x + bout
#pragma unroll
        for (int j = 0; j < 5; ++j) w1[0][j] = Wout[j];
        bA[0] = bout[0];
    }

    // ---- pre (gi0 slice) LDS addressing; non-readers point at zrow --------
    const bool rdr  = (quad == 0 && qlane < 3);
    float* lptr     = rdr ? &gbuf[0][0][grp][qlane * 5] : zrow;
    const int str   = rdr ? 64 : 0;        // floats per timestep row
    const int cstr  = rdr ? CT * 64 : 0;   // floats per chunk buffer

    float h[5]   = {0.f, 0.f, 0.f, 0.f, 0.f};
    float pre[5] = {0.f, 0.f, 0.f, 0.f, 0.f};

    __syncthreads();                       // chunk 0 staged
    PREF(0, 0);

    for (int c = 0; c < NCH; ++c) {
        const int cb = c & 1;
#pragma unroll 2
        for (int tl = 0; tl < CT; ++tl) {
            const int s = c * CT + tl;
            GSTEP(s, if (tl + 1 < CT) { PREF(cb, tl + 1); });
        }
        __syncthreads();                   // chunk c done; chunk c+1 published
        if (c + 1 < NCH) { PREF((c + 1) & 1, 0); }
    }

    // drain: 3 wall steps flush the layer pipeline (pre stale but h masked)
    for (int s = T_DIM; s < T_DIM + 3; ++s) {
        GSTEP(s, ;);
    }
}

// ---------------------------------------------------------------------------
extern "C" void kernel_launch(void* const* d_in, const int* in_sizes, int n_in,
                              void* d_out, int out_size, void* d_ws, size_t ws_size,
                              hipStream_t stream)
{
    (void)in_sizes; (void)n_in; (void)out_size; (void)ws_size;

    const float* X    = (const float*)d_in[0];
    const float* W1   = (const float*)d_in[1];
    const float* b1   = (const float*)d_in[2];
    const float* W2   = (const float*)d_in[3];
    const float* b2   = (const float*)d_in[4];
    const float* W3   = (const float*)d_in[5];
    const float* b3   = (const float*)d_in[6];
    const float* wih0 = (const float*)d_in[7];
    const float* whh0 = (const float*)d_in[8];
    const float* bih0 = (const float*)d_in[9];
    const float* bhh0 = (const float*)d_in[10];
    const float* wih1 = (const float*)d_in[11];
    const float* whh1 = (const float*)d_in[12];
    const float* bih1 = (const float*)d_in[13];
    const float* bhh1 = (const float*)d_in[14];
    const float* wih2 = (const float*)d_in[15];
    const float* whh2 = (const float*)d_in[16];
    const float* bih2 = (const float*)d_in[17];
    const float* bhh2 = (const float*)d_in[18];
    const float* Wout = (const float*)d_in[19];
    const float* bout = (const float*)d_in[20];

    ushort* Wp  = (ushort*)d_ws;                       // 400 frags * 1 KB = 400 KB
    float*  gi0 = (float*)((char*)d_ws + 524288);      // (32768, 16) fp32 = 2 MB

    pack_w1_kernel<<<NSTEP, 256, 0, stream>>>(W1, Wp);
    mlp_kernel<<<512, 256, 0, stream>>>(X, Wp, b1, W2, b2, W3, b3, wih0, bih0, gi0);
    gru_kernel<<<32, 128, 0, stream>>>(gi0, whh0, bhh0,
                                       wih1, whh1, bih1, bhh1,
                                       wih2, whh2, bih2, bhh2,
                                       Wout, bout, (float*)d_out);
}

// Round 9
// 115.893 us; speedup vs baseline: 2.5189x; 1.7664x over previous
//
#include <hip/hip_runtime.h>
#include <hip/hip_bf16.h>

// ---------------------------------------------------------------------------
// RnnGruModel: MLP (1600->60->15->10) fused with GRU-layer0 input-gate
// precompute, then 3 stacked GRU layers (H=5) + output projection.
// X@W1^T done in bf16 MFMA with hi/lo split (3 products) -> ~fp32 accuracy.
// GRU: systolic layer pipeline, ONE BATCH PER WAVE, ONE GATE PER LANE.
//   wave = 4 rows of 16 lanes. row r (0..2) = GRU layer r at t = s - r;
//   row 3 = output projection (lane 48). lane g<15 of a layer-row owns gate g
//   (r:0-4, z:5-9, n:10-14) -> dots are 10 fma INSTRUCTIONS, transcendentals
//   are 1 sigmoid + 1 tanh chain per step (wave-parallel across 45 gates).
//   r/z -> n-lane via DPP row_shr:10 / row_shr:5; h/x replication via 10
//   independent ds_bpermute (constant addrs) once per step.
// gi0 staged by a producer wave (CT=32 double-buffered LDS ring). gi0 col 15
// is zero-padded by mlp_kernel -> free zero "pre" for rows 1..3.
// Layouts: X (T,B,F) row-major, row r = t*128 + b.  Output (T,1,B): t*128+b.
// ---------------------------------------------------------------------------

#define T_DIM 256
#define B_DIM 128
#define F_DIM 1600
#define H1_DIM 60
#define H2_DIM 15
#define H3_DIM 10
#define GH 5
#define NSTEP 50          // MLP K-steps of 32 (1600/32)
#define CT 32             // GRU LDS chunk: timesteps per buffer
#define NCH (T_DIM / CT)  // 8 chunks

#define DPP_SHR5  0x115   // row_shr:5  (lane i <- lane i-5 within 16-lane row)
#define DPP_SHR10 0x11A   // row_shr:10 (lane i <- lane i-10)

typedef __attribute__((ext_vector_type(8))) short bf16x8;   // MFMA A/B frag (4 VGPRs)
typedef __attribute__((ext_vector_type(4))) float f32x4;    // MFMA C/D frag

__device__ __forceinline__ float fast_tanh(float x) {
    float e = __expf(2.0f * x);
    return 1.0f - __fdividef(2.0f, e + 1.0f);   // safe at +-inf
}
__device__ __forceinline__ float fast_sigmoid(float x) {
    return __fdividef(1.0f, 1.0f + __expf(-x)); // safe at +-inf
}
__device__ __forceinline__ ushort f2bf_rn(float x) {        // round-to-nearest bf16
    uint u = __float_as_uint(x);
    u += 0x7fffu + ((u >> 16) & 1u);
    return (ushort)(u >> 16);
}
template <int CTRL>
__device__ __forceinline__ float dppf(float v) {
    return __int_as_float(
        __builtin_amdgcn_mov_dpp(__float_as_int(v), CTRL, 0xf, 0xf, true));
}
__device__ __forceinline__ float bperm(int addr, float v) {
    return __int_as_float(__builtin_amdgcn_ds_bpermute(addr, __float_as_int(v)));
}

// ---------------------------------------------------------------------------
// Kernel 0: pack W1 (60x1600 fp32, zero-padded to 64 rows) into frag-ordered
// bf16 hi/lo pairs (unchanged, verified).
// ---------------------------------------------------------------------------
__global__ __launch_bounds__(256) void pack_w1_kernel(
    const float* __restrict__ W1, ushort* __restrict__ Wp)
{
    const int s  = blockIdx.x;       // 0..49
    const int t  = threadIdx.x;
    const int nf = t >> 6;
    const int l  = t & 63;
    const int n  = nf * 16 + (l & 15);
    const int g  = l >> 4;

    ushort hi[8], lo[8];
#pragma unroll
    for (int j = 0; j < 8; ++j) {
        const int k = s * 32 + g * 8 + j;
        const float v = (n < H1_DIM) ? W1[n * F_DIM + k] : 0.0f;
        const ushort h = f2bf_rn(v);
        const float hf = __uint_as_float(((uint)h) << 16);
        const float r  = v - hf;                       // exact
        hi[j] = h;
        lo[j] = (ushort)(__float_as_uint(r) >> 16);    // truncate: |err| ~ 2^-17 |v|
    }
    ushort* dst = Wp + ((size_t)(s * 8 + nf * 2)) * 512 + l * 8;
#pragma unroll
    for (int j = 0; j < 8; ++j) dst[j] = hi[j];
#pragma unroll
    for (int j = 0; j < 8; ++j) dst[512 + j] = lo[j];
}

// ---------------------------------------------------------------------------
// Kernel 1: per-row MLP + gi0 precompute, MFMA edition (unchanged, verified).
// ---------------------------------------------------------------------------
__global__ __launch_bounds__(256) void mlp_kernel(
    const float* __restrict__ X,
    const ushort* __restrict__ Wp,
    const float* __restrict__ b1,
    const float* __restrict__ W2, const float* __restrict__ b2,
    const float* __restrict__ W3, const float* __restrict__ b3,
    const float* __restrict__ wih0, const float* __restrict__ bih0,
    float* __restrict__ gi0)
{
    __shared__ float red[4 * 4096];   // 64 KB: per-wave 64x64 C partials

    const int tid  = threadIdx.x;
    const int l    = tid & 63;
    const int w    = __builtin_amdgcn_readfirstlane(tid >> 6);
    const int lm   = l & 15;          // A-row / B-col lane index
    const int g    = l >> 4;          // k-slot group
    const int row0 = blockIdx.x * 64;

    f32x4 acc[4][4];
#pragma unroll
    for (int mf = 0; mf < 4; ++mf)
#pragma unroll
        for (int nf = 0; nf < 4; ++nf)
            acc[mf][nf] = (f32x4){0.f, 0.f, 0.f, 0.f};

    const int s0 = (w * NSTEP) >> 2;        // 0,12,25,37
    const int s1 = ((w + 1) * NSTEP) >> 2;  // 12,25,37,50

    for (int s = s0; s < s1; ++s) {
        bf16x8 bh[4], bl[4];
        const ushort* wp_s = Wp + (size_t)s * 4096 + l * 8;
#pragma unroll
        for (int nf = 0; nf < 4; ++nf) {
            bh[nf] = *(const bf16x8*)(wp_s + (nf * 2 + 0) * 512);
            bl[nf] = *(const bf16x8*)(wp_s + (nf * 2 + 1) * 512);
        }
        bf16x8 a_hi[4], a_lo[4];
#pragma unroll
        for (int mf = 0; mf < 4; ++mf) {
            const float* ap = X + (size_t)(row0 + mf * 16 + lm) * F_DIM + s * 32 + g * 8;
            const float4 x0 = *(const float4*)ap;
            const float4 x1 = *(const float4*)(ap + 4);
            const float xs8[8] = {x0.x, x0.y, x0.z, x0.w, x1.x, x1.y, x1.z, x1.w};
            bf16x8 ah, al;
#pragma unroll
            for (int j = 0; j < 8; ++j) {
                const float v = xs8[j];
                const uint  u = __float_as_uint(v);
                const uint uh = (u + 0x7fffu + ((u >> 16) & 1u)) & 0xffff0000u;
                const float hf = __uint_as_float(uh);
                const float r  = v - hf;               // exact
                ah[j] = (short)(uh >> 16);
                al[j] = (short)(__float_as_uint(r) >> 16);
            }
            a_hi[mf] = ah; a_lo[mf] = al;
        }
#pragma unroll
        for (int mf = 0; mf < 4; ++mf)
#pragma unroll
            for (int nf = 0; nf < 4; ++nf) {
                f32x4 c = acc[mf][nf];
                c = __builtin_amdgcn_mfma_f32_16x16x32_bf16(a_lo[mf], bh[nf], c, 0, 0, 0);
                c = __builtin_amdgcn_mfma_f32_16x16x32_bf16(a_hi[mf], bl[nf], c, 0, 0, 0);
                c = __builtin_amdgcn_mfma_f32_16x16x32_bf16(a_hi[mf], bh[nf], c, 0, 0, 0);
                acc[mf][nf] = c;
            }
    }

    float* myred = red + w * 4096;
#pragma unroll
    for (int mf = 0; mf < 4; ++mf)
#pragma unroll
        for (int nf = 0; nf < 4; ++nf)
#pragma unroll
            for (int q = 0; q < 4; ++q)
                myred[(mf * 16 + g * 4 + q) * 64 + nf * 16 + lm] = acc[mf][nf][q];
    __syncthreads();

    float rsum[16];
#pragma unroll
    for (int i = 0; i < 16; ++i) {
        const int p = tid + 256 * i;
        rsum[i] = red[p] + red[4096 + p] + red[8192 + p] + red[12288 + p];
    }
    __syncthreads();
    float* redp = red + 8192;              // 64 x 65 padded
#pragma unroll
    for (int i = 0; i < 16; ++i) {
        const int p = tid + 256 * i;
        redp[(p >> 6) * 65 + (p & 63)] = rsum[i];
    }
    __syncthreads();
    if (w != 0) return;

    float h1v[H1_DIM];
#pragma unroll
    for (int o = 0; o < H1_DIM; ++o)
        h1v[o] = fast_tanh(redp[l * 65 + o] + b1[o]);

    float h2v[H2_DIM];
#pragma unroll
    for (int j = 0; j < H2_DIM; ++j) {
        float sacc = b2[j];
#pragma unroll
        for (int o = 0; o < H1_DIM; ++o) sacc += W2[j * H1_DIM + o] * h1v[o];
        h2v[j] = fast_tanh(sacc);
    }

    float h3v[H3_DIM];
#pragma unroll
    for (int m = 0; m < H3_DIM; ++m) {
        float sacc = b3[m];
#pragma unroll
        for (int j = 0; j < H2_DIM; ++j) sacc += W3[m * H2_DIM + j] * h2v[j];
        h3v[m] = sacc;
    }

    float gv[15];
#pragma unroll
    for (int q = 0; q < 15; ++q) {
        float sacc = bih0[q];
#pragma unroll
        for (int m = 0; m < H3_DIM; ++m) sacc += wih0[q * H3_DIM + m] * h3v[m];
        gv[q] = sacc;
    }

    const int row = row0 + l;
    float4* dst = (float4*)(gi0 + (size_t)row * 16);
    dst[0] = make_float4(gv[0],  gv[1],  gv[2],  gv[3]);
    dst[1] = make_float4(gv[4],  gv[5],  gv[6],  gv[7]);
    dst[2] = make_float4(gv[8],  gv[9],  gv[10], gv[11]);
    dst[3] = make_float4(gv[12], gv[13], gv[14], 0.0f);
}

// ---------------------------------------------------------------------------
// Kernel 2: systolic GRU, one batch per wave, one gate per lane.
// Grid: 128 blocks x 128 threads (block = 1 batch; wave0 compute, wave1
// producer staging gi0 chunks into a CT=32 double-buffered LDS ring).
// ---------------------------------------------------------------------------

// producer: stage chunk C into gbuf[C&1]; 128 float4 per chunk, 2 per lane
#define STAGE(C) do {                                                       \
    const int _cb = (C) & 1;                                                \
    float4 _v0, _v1;                                                        \
    {                                                                       \
        const int _t = lane >> 2, _q = lane & 3;                            \
        _v0 = *(const float4*)(gi0 +                                        \
            ((size_t)(((C) * CT + _t) * B_DIM + b)) * 16 + _q * 4);         \
    }                                                                       \
    {                                                                       \
        const int _f = lane + 64, _t = _f >> 2, _q = _f & 3;                \
        _v1 = *(const float4*)(gi0 +                                        \
            ((size_t)(((C) * CT + _t) * B_DIM + b)) * 16 + _q * 4);         \
    }                                                                       \
    *(float4*)&gbuf[_cb][lane >> 2][(lane & 3) * 4] = _v0;                  \
    *(float4*)&gbuf[_cb][(lane + 64) >> 2][((lane + 64) & 3) * 4] = _v1;    \
} while (0)

#define PREF(CB, TL) do { pre = lptr[(CB) * (CT * 16) + (TL) * 16]; } while (0)

#define GSTEP(S, PREFCODE) do {                                             \
    /* dots: aA = bA(+gi) + wi.x ; aB = bB + wh.h  (ref-exact order) */     \
    float aA = bA + pre;                                                    \
    _Pragma("unroll") for (int _j = 0; _j < GH; ++_j)                       \
        aA = fmaf(wi[_j], xn[_j], aA);                                      \
    float aB = fmaf(wh[0], hn[0], bB);                                      \
    _Pragma("unroll") for (int _j = 1; _j < GH; ++_j)                       \
        aB = fmaf(wh[_j], hn[_j], aB);                                      \
    PREFCODE                                                                \
    const float sAv = aA + aB;                                              \
    const float sg  = fast_sigmoid(sAv);                                    \
    const float rn  = dppf<DPP_SHR10>(sg);   /* r_i -> n-lane (g-10) */     \
    const float zn  = dppf<DPP_SHR5>(sg);    /* z_i -> n-lane (g-5)  */     \
    if (lane == 48 && (unsigned)((S) - 3) < (unsigned)T_DIM)                \
        out[((S) - 3) * B_DIM + b] = sAv;    /* projection pre-activation */\
    const float nv = fast_tanh(fmaf(rn, aB, aA));                           \
    const float hu = fmaf(zn, hm - nv, nv);                                 \
    const bool _valid = (unsigned)((S) - row) < (unsigned)T_DIM;            \
    hm = _valid ? hu : hm;                                                  \
    /* replicate h (own row) and x (prev row) for next step */              \
    _Pragma("unroll") for (int _j = 0; _j < GH; ++_j) {                     \
        hn[_j] = bperm(a_self[_j], hm);                                     \
        xn[_j] = bperm(a_prev[_j], hm);                                     \
    }                                                                       \
} while (0)

__global__ __launch_bounds__(128, 1) void gru_kernel(
    const float* __restrict__ gi0,
    const float* __restrict__ whh0, const float* __restrict__ bhh0,
    const float* __restrict__ wih1, const float* __restrict__ whh1,
    const float* __restrict__ bih1, const float* __restrict__ bhh1,
    const float* __restrict__ wih2, const float* __restrict__ whh2,
    const float* __restrict__ bih2, const float* __restrict__ bhh2,
    const float* __restrict__ Wout, const float* __restrict__ bout,
    float* __restrict__ out)
{
    __shared__ float gbuf[2][CT][16];      // 4 KB double-buffered gi0 chunks

    const int tid  = threadIdx.x;
    const int w    = __builtin_amdgcn_readfirstlane(tid >> 6);
    const int lane = tid & 63;
    const int b    = blockIdx.x;           // one batch per block

    if (w == 1) {
        // ---------------- producer wave ----------------
        STAGE(0);
        __syncthreads();                   // chunk 0 visible
        for (int c = 0; c < NCH; ++c) {
            if (c + 1 < NCH) STAGE(c + 1);
            __syncthreads();               // publish chunk c+1; consumer done with c
        }
        return;
    }

    // ---------------- consumer wave ----------------
    const int row = lane >> 4;             // 0..2 = layer, 3 = projection
    const int g   = lane & 15;             // gate (r:0-4, z:5-9, n:10-14)

    // ---- per-lane weights: ONE gate row ----
    float wi[GH], wh[GH];
    float bA = 0.f, bB = 0.f;
#pragma unroll
    for (int j = 0; j < GH; ++j) { wi[j] = 0.f; wh[j] = 0.f; }

    if (row == 0) {
        if (g < 15) {                      // L0: x-side is in gi0 (incl. bih0)
#pragma unroll
            for (int j = 0; j < GH; ++j) wh[j] = whh0[g * GH + j];
            bB = bhh0[g];
        }
    } else if (row < 3) {
        const float* wip = (row == 1) ? wih1 : wih2;
        const float* whp = (row == 1) ? whh1 : whh2;
        const float* bip = (row == 1) ? bih1 : bih2;
        const float* bhp = (row == 1) ? bhh1 : bhh2;
        if (g < 15) {
#pragma unroll
            for (int j = 0; j < GH; ++j) {
                wi[j] = wip[g * GH + j];
                wh[j] = whp[g * GH + j];
            }
            bA = bip[g];
            bB = bhp[g];
        }
    } else if (g == 0) {                   // projection: y = Wout.h2 + bout
#pragma unroll
        for (int j = 0; j < GH; ++j) wi[j] = Wout[j];
        bA = bout[0];
    }

    // ---- bpermute addresses (constant): n-lanes of own / previous row ----
    int a_self[GH], a_prev[GH];
    const int sbase = row * 16;
    const int pbase = ((row + 3) & 3) * 16;    // row-1 mod 4 (row0 wraps; x*0)
#pragma unroll
    for (int j = 0; j < GH; ++j) {
        a_self[j] = (sbase + 10 + j) << 2;
        a_prev[j] = (pbase + 10 + j) << 2;
    }

    // ---- pre (gi0) LDS column: row0 lane g -> col g; others -> col 15 (=0)
    const float* lptr = &gbuf[0][0][(row == 0) ? g : 15];

    float hn[GH] = {0.f, 0.f, 0.f, 0.f, 0.f};
    float xn[GH] = {0.f, 0.f, 0.f, 0.f, 0.f};
    float hm = 0.f, pre = 0.f;

    __syncthreads();                       // chunk 0 staged
    PREF(0, 0);

    for (int c = 0; c < NCH; ++c) {
        const int cb = c & 1;
#pragma unroll 2
        for (int tl = 0; tl < CT; ++tl) {
            const int s = c * CT + tl;
            GSTEP(s, if (tl + 1 < CT) { PREF(cb, tl + 1); });
        }
        __syncthreads();                   // chunk c done; chunk c+1 published
        if (c + 1 < NCH) { PREF((c + 1) & 1, 0); }
    }

    // drain: 3 wall steps flush the layer pipeline (pre stale but h masked)
    for (int s = T_DIM; s < T_DIM + 3; ++s) {
        GSTEP(s, ;);
    }
}

// ---------------------------------------------------------------------------
extern "C" void kernel_launch(void* const* d_in, const int* in_sizes, int n_in,
                              void* d_out, int out_size, void* d_ws, size_t ws_size,
                              hipStream_t stream)
{
    (void)in_sizes; (void)n_in; (void)out_size; (void)ws_size;

    const float* X    = (const float*)d_in[0];
    const float* W1   = (const float*)d_in[1];
    const float* b1   = (const float*)d_in[2];
    const float* W2   = (const float*)d_in[3];
    const float* b2   = (const float*)d_in[4];
    const float* W3   = (const float*)d_in[5];
    const float* b3   = (const float*)d_in[6];
    const float* wih0 = (const float*)d_in[7];
    const float* whh0 = (const float*)d_in[8];
    const float* bih0 = (const float*)d_in[9];
    const float* bhh0 = (const float*)d_in[10];
    const float* wih1 = (const float*)d_in[11];
    const float* whh1 = (const float*)d_in[12];
    const float* bih1 = (const float*)d_in[13];
    const float* bhh1 = (const float*)d_in[14];
    const float* wih2 = (const float*)d_in[15];
    const float* whh2 = (const float*)d_in[16];
    const float* bih2 = (const float*)d_in[17];
    const float* bhh2 = (const float*)d_in[18];
    const float* Wout = (const float*)d_in[19];
    const float* bout = (const float*)d_in[20];

    ushort* Wp  = (ushort*)d_ws;                       // 400 frags * 1 KB = 400 KB
    float*  gi0 = (float*)((char*)d_ws + 524288);      // (32768, 16) fp32 = 2 MB

    pack_w1_kernel<<<NSTEP, 256, 0, stream>>>(W1, Wp);
    mlp_kernel<<<512, 256, 0, stream>>>(X, Wp, b1, W2, b2, W3, b3, wih0, bih0, gi0);
    gru_kernel<<<128, 128, 0, stream>>>(gi0, whh0, bhh0,
                                        wih1, whh1, bih1, bhh1,
                                        wih2, whh2, bih2, bhh2,
                                        Wout, bout, (float*)d_out);
}